// Round 4
// baseline (439.299 us; speedup 1.0000x reference)
//
#include <hip/hip_runtime.h>
#include <hip/hip_bf16.h>

// SpatiotemporalAttention — bf16 MFMA pipeline, round 4.
// B=4, C=256, CI=128, N=48*48=2304.
//
// Round-4 changes (occupancy fixes, counter-driven):
//   y-gemm: split-K 6 -> 864 blocks, f32 atomic partials (YTF) + yreduce pass
//   e_time: ksplit 36 -> 144 blocks
//   P row/col sums fused into e_space epilogue (rowsum/colsum kernels deleted)

#define N_PIX 2304
#define NB 4

typedef __attribute__((ext_vector_type(8))) short bf16x8;
typedef __attribute__((ext_vector_type(4))) float f32x4;

__device__ __forceinline__ short f2bf(float f) {
  unsigned u = __float_as_uint(f);
  unsigned r = (u + 0x7fffu + ((u >> 16) & 1u)) >> 16;
  return (short)r;
}
__device__ __forceinline__ float bf2f(short s) {
  return __uint_as_float(((unsigned)(unsigned short)s) << 16);
}
__device__ __forceinline__ int swz(int row, int kc) {
  return kc ^ ((row ^ (row >> 3)) & 7);
}
__device__ __forceinline__ unsigned pk2(short a, short b) {
  return (unsigned)(unsigned short)a | ((unsigned)(unsigned short)b << 16);
}

// ---------------- workspace layout (byte offsets) ----------------
// BPRE   f32[512]            @ 0
// BPOST  f32[512]            @ 2048
// CS     f32[4*2304]         @ 4096      (colsum of P: CS[m]=sum_n P[n][m])
// RS     f32[4*2304]         @ 40960     (rowsum of P: RS[m]=sum_n P[m][n])
// ET     f32[4*128*128]      @ 77824
// WPREH  bf16[2*256*256]     @ 339968
// WPREL  bf16[2*256*256]     @ 602112
// WPOSTB bf16[2*256*128]     @ 864256
// MB     bf16[2*4*128*128]   @ 995328    (M1 then M2)
// XTH    bf16[2*4*2304*256]  @ 1257472   (x^T hi)
// XTL    bf16[2*4*2304*256]  @ 10694656
// FB     bf16[2*4*128*2304]  @ 20131840  (theta/phi rows only, natural)
// FLO    bf16[2*4*128*2304]  @ 24850432
// FTB    bf16[2*4*2304*256]  @ 29569024  (F^T, all rows)
// FTLO   bf16[2*4*2304*128]  @ 39006208  (F^T lo, theta/phi cols only)
// AB     bf16[2*4*128*2304]  @ 43724800
// YT     bf16[2*4*2304*128]  @ 48443392  (y^T)
// PT     bf16[4*2304*2304]   @ 53161984  (PT[a][b] = exp(E[b][a]))
// YTF    f32[2*4*2304*128]   @ 95629312  (y^T split-K partials)
// total ~105 MB

struct GArgs {
  const short *a0, *a1, *al0, *al1;
  const short *b0, *b1, *bl0, *bl1;
  long sa, sb, sal, sbl;
  int lda, ldb, lal, lbl;
  int K, ksplit, kchunk;
  int bt0, bt1;                       // B stored [K][N] -> transpose-stage
  void *o0, *o1; long so;
  void *p0, *p1; long sp;
  void *q0, *q1; long sq;
  void *u0, *u1; long su;
  const float *aux0, *aux1; long saux;  // bias (EPI0/5)
  const float *res0, *res1; long sres;  // residual (EPI5)
};

// EPI: 0=pre(F_b/F_lo/FT_b/FT_lo + bias)  1=e_time(atomic f32)
//      2=ESP(exp -> PT, fused CS/RS atomic sums)  3=A(bf16 natural)
//      5=post(f32+bias+resid)  6=y split-K (atomic f32 -> YTF)
template <int EPI, int SPLIT>
__global__ __launch_bounds__(256) void mgemm(GArgs g) {
  int z = blockIdx.z;
  int pb = z / g.ksplit, ks = z - pb * g.ksplit;
  int sel = pb >> 2, batch = pb & 3;
  const short* A = (sel ? g.a1 : g.a0) + (long)batch * g.sa;
  const short* B = (sel ? g.b1 : g.b0) + (long)batch * g.sb;
  const short* Al = nullptr; const short* Bl = nullptr;
  if (SPLIT) {
    Al = (sel ? g.al1 : g.al0) + (long)batch * g.sal;
    Bl = (sel ? g.bl1 : g.bl0) + (long)batch * g.sbl;
  }
  int bt = sel ? g.bt1 : g.bt0;
  int k0 = ks * g.kchunk, k1 = k0 + g.kchunk;
  int m0 = blockIdx.y << 7, n0 = blockIdx.x << 7;

  __shared__ short As[128 * 64];
  __shared__ short Bs[128 * 64];
  __shared__ short Als[SPLIT ? 128 * 64 : 8];
  __shared__ short Bls[SPLIT ? 128 * 64 : 8];

  int t = threadIdx.x;
  int lane = t & 63, wid = t >> 6;
  int wm = (wid >> 1) << 6, wn = (wid & 1) << 6;
  int l15 = lane & 15, lg = lane >> 4;

  f32x4 acc[4][4];
  #pragma unroll
  for (int i = 0; i < 4; ++i)
    #pragma unroll
    for (int j = 0; j < 4; ++j) acc[i][j] = (f32x4){0.f, 0.f, 0.f, 0.f};

  for (int kt = k0; kt < k1; kt += 64) {
    __syncthreads();
    #pragma unroll
    for (int i = 0; i < 4; ++i) {
      int ch = t + (i << 8);
      int row = ch >> 3, kc = ch & 7;
      int di = (row << 6) + (swz(row, kc) << 3);
      *(bf16x8*)&As[di] = *(const bf16x8*)&A[(long)(m0 + row) * g.lda + kt + (kc << 3)];
      if (SPLIT)
        *(bf16x8*)&Als[di] = *(const bf16x8*)&Al[(long)(m0 + row) * g.lal + kt + (kc << 3)];
    }
    if (!bt) {
      #pragma unroll
      for (int i = 0; i < 4; ++i) {
        int ch = t + (i << 8);
        int row = ch >> 3, kc = ch & 7;
        int di = (row << 6) + (swz(row, kc) << 3);
        *(bf16x8*)&Bs[di] = *(const bf16x8*)&B[(long)(n0 + row) * g.ldb + kt + (kc << 3)];
        if (SPLIT)
          *(bf16x8*)&Bls[di] = *(const bf16x8*)&Bl[(long)(n0 + row) * g.lbl + kt + (kc << 3)];
      }
    } else {
      // B stored [K][N']: coalesced row reads, transposed scatter into LDS
      #pragma unroll
      for (int i = 0; i < 4; ++i) {
        int ch = t + (i << 8);
        int nc = ch & 15, kk = ch >> 4;
        bf16x8 ld = *(const bf16x8*)&B[(long)(kt + kk) * g.ldb + n0 + (nc << 3)];
        int kc = kk >> 3, w = kk & 7;
        #pragma unroll
        for (int e = 0; e < 8; ++e) {
          int rn = (nc << 3) + e;
          Bs[(rn << 6) + (swz(rn, kc) << 3) + w] = ld[e];
        }
      }
    }
    __syncthreads();
    #pragma unroll
    for (int ksub = 0; ksub < 2; ++ksub) {
      int kb = (ksub << 2) + lg;
      bf16x8 ah[4], bh[4], alv[4], blv[4];
      #pragma unroll
      for (int i = 0; i < 4; ++i) {
        int ra = wm + (i << 4) + l15;
        int rb = wn + (i << 4) + l15;
        ah[i] = *(const bf16x8*)&As[(ra << 6) + (swz(ra, kb) << 3)];
        bh[i] = *(const bf16x8*)&Bs[(rb << 6) + (swz(rb, kb) << 3)];
        if (SPLIT) {
          alv[i] = *(const bf16x8*)&Als[(ra << 6) + (swz(ra, kb) << 3)];
          blv[i] = *(const bf16x8*)&Bls[(rb << 6) + (swz(rb, kb) << 3)];
        }
      }
      #pragma unroll
      for (int i = 0; i < 4; ++i)
        #pragma unroll
        for (int j = 0; j < 4; ++j) {
          if (SPLIT) {
            acc[i][j] = __builtin_amdgcn_mfma_f32_16x16x32_bf16(alv[i], bh[j], acc[i][j], 0, 0, 0);
            acc[i][j] = __builtin_amdgcn_mfma_f32_16x16x32_bf16(ah[i], blv[j], acc[i][j], 0, 0, 0);
          }
          acc[i][j] = __builtin_amdgcn_mfma_f32_16x16x32_bf16(ah[i], bh[j], acc[i][j], 0, 0, 0);
        }
    }
  }

  // ---------------- epilogue ----------------
  float rsacc[16];
  if (EPI == 2) {
    #pragma unroll
    for (int q = 0; q < 16; ++q) rsacc[q] = 0.f;
  }
  #pragma unroll
  for (int j = 0; j < 4; ++j) {
    int col = n0 + wn + (j << 4) + l15;
    float csacc = 0.f;
    #pragma unroll
    for (int i = 0; i < 4; ++i) {
      int row0 = m0 + wm + (i << 4) + (lg << 2);
      if (EPI == 0) {
        const float* bias = (sel ? g.aux1 : g.aux0);
        short* FTB_ = (short*)(sel ? g.q1 : g.q0) + (long)batch * g.sq;
        float v[4]; short hh[4];
        #pragma unroll
        for (int r = 0; r < 4; ++r) { v[r] = acc[i][j][r] + bias[row0 + r]; hh[r] = f2bf(v[r]); }
        uint2 pk; pk.x = pk2(hh[0], hh[1]); pk.y = pk2(hh[2], hh[3]);
        *(uint2*)&FTB_[(long)col * 256 + row0] = pk;
        if (row0 >= 128) {
          short* FB_  = (short*)(sel ? g.o1 : g.o0) + (long)batch * g.so;
          short* FLO_ = (short*)(sel ? g.p1 : g.p0) + (long)batch * g.sp;
          short* FTL_ = (short*)(sel ? g.u1 : g.u0) + (long)batch * g.su;
          short ll[4];
          #pragma unroll
          for (int r = 0; r < 4; ++r) {
            ll[r] = f2bf(v[r] - bf2f(hh[r]));
            FB_[(long)(row0 - 128 + r) * N_PIX + col] = hh[r];
            FLO_[(long)(row0 - 128 + r) * N_PIX + col] = ll[r];
          }
          uint2 pl; pl.x = pk2(ll[0], ll[1]); pl.y = pk2(ll[2], ll[3]);
          *(uint2*)&FTL_[(long)col * 128 + (row0 - 128)] = pl;
        }
      } else if (EPI == 1) {
        float* ET_ = (float*)g.o0 + (long)batch * g.so;
        #pragma unroll
        for (int r = 0; r < 4; ++r) atomicAdd(&ET_[(long)(row0 + r) * 128 + col], acc[i][j][r]);
      } else if (EPI == 2) {
        short* PT_ = (short*)g.o0 + (long)batch * g.so;
        short hh[4];
        #pragma unroll
        for (int r = 0; r < 4; ++r) {
          float ev = __expf(acc[i][j][r]);
          hh[r] = f2bf(ev);
          csacc += ev;
          rsacc[(i << 2) + r] += ev;
        }
        uint2 pk; pk.x = pk2(hh[0], hh[1]); pk.y = pk2(hh[2], hh[3]);
        *(uint2*)&PT_[(long)col * N_PIX + row0] = pk;
      } else if (EPI == 3) {
        short* AB_ = (short*)(sel ? g.o1 : g.o0) + (long)batch * g.so;
        #pragma unroll
        for (int r = 0; r < 4; ++r) AB_[(long)(row0 + r) * N_PIX + col] = f2bf(acc[i][j][r]);
      } else if (EPI == 6) {
        float* YTF_ = (float*)(sel ? g.o1 : g.o0) + (long)batch * g.so;
        #pragma unroll
        for (int r = 0; r < 4; ++r) atomicAdd(&YTF_[(long)col * 128 + row0 + r], acc[i][j][r]);
      } else {
        float* O_ = (float*)(sel ? g.o1 : g.o0) + (long)batch * g.so;
        const float* bias = (sel ? g.aux1 : g.aux0);
        const float* R_ = (sel ? g.res1 : g.res0) + (long)batch * g.sres;
        #pragma unroll
        for (int r = 0; r < 4; ++r)
          O_[(long)(row0 + r) * N_PIX + col] =
              acc[i][j][r] + bias[row0 + r] + R_[(long)(row0 + r) * N_PIX + col];
      }
    }
    if (EPI == 2) {
      // CS[col] += sum over this block's rows: reduce across lg (lanes ^16, ^32)
      csacc += __shfl_xor(csacc, 16, 64);
      csacc += __shfl_xor(csacc, 32, 64);
      if (lg == 0) {
        float* CSb = (float*)g.p0 + (long)batch * N_PIX;
        atomicAdd(&CSb[col], csacc);
      }
    }
  }
  if (EPI == 2) {
    // RS[row] += sum over this block's cols: reduce across l15 (lanes ^1,^2,^4,^8)
    float* RSb = (float*)g.q0 + (long)batch * N_PIX;
    #pragma unroll
    for (int i = 0; i < 4; ++i)
      #pragma unroll
      for (int r = 0; r < 4; ++r) {
        float v = rsacc[(i << 2) + r];
        v += __shfl_xor(v, 1, 64);
        v += __shfl_xor(v, 2, 64);
        v += __shfl_xor(v, 4, 64);
        v += __shfl_xor(v, 8, 64);
        if (l15 == 0) atomicAdd(&RSb[m0 + wm + (i << 4) + (lg << 2) + r], v);
      }
  }
}

// ---------------- helper kernels ----------------

__global__ __launch_bounds__(256) void xcast(const float* __restrict__ x1,
                                             const float* __restrict__ x2,
                                             short* __restrict__ XH, short* __restrict__ XL) {
  __shared__ float tile[32][33];
  int z = blockIdx.z; int sel = z >> 2, b = z & 3;
  const float* X = (sel ? x2 : x1) + (long)b * 256 * N_PIX;
  long obase = ((long)(sel * 4 + b)) * N_PIX * 256;
  int n0 = blockIdx.x << 5, c0 = blockIdx.y << 5;
  int tx = threadIdx.x & 31, ty = threadIdx.x >> 5;
  #pragma unroll
  for (int i = 0; i < 4; ++i)
    tile[ty + (i << 3)][tx] = X[(long)(c0 + ty + (i << 3)) * N_PIX + n0 + tx];
  __syncthreads();
  #pragma unroll
  for (int i = 0; i < 4; ++i) {
    int n = n0 + ty + (i << 3);
    float v = tile[tx][ty + (i << 3)];
    short h = f2bf(v);
    XH[obase + (long)n * 256 + c0 + tx] = h;
    XL[obase + (long)n * 256 + c0 + tx] = f2bf(v - bf2f(h));
  }
}

__global__ __launch_bounds__(256) void fold_pre(const float* __restrict__ bn,
                                                const float* __restrict__ w,
                                                const float* __restrict__ b,
                                                short* __restrict__ WH, short* __restrict__ WL,
                                                float* __restrict__ Bc) {
  int blk = blockIdx.x;
  int xsel = blk >> 8, row = blk & 255;
  int i = (row < 128) ? xsel : (2 + xsel);
  int o = row & 127;
  int c = threadIdx.x;
  const float* bni = bn + i * 1024;
  float gm = bni[c], be = bni[256 + c], mn = bni[512 + c], vr = bni[768 + c];
  float s = gm * rsqrtf(vr + 1e-5f);
  float tb = be - mn * s;
  float wv = w[(i * 128 + o) * 256 + c];
  float val = wv * s;
  short h = f2bf(val);
  long idx = (long)(xsel * 256 + row) * 256 + c;
  WH[idx] = h;
  WL[idx] = f2bf(val - bf2f(h));
  __shared__ float red[256];
  red[c] = wv * tb;
  __syncthreads();
  for (int off = 128; off > 0; off >>= 1) {
    if (c < off) red[c] += red[c + off];
    __syncthreads();
  }
  if (c == 0) Bc[xsel * 256 + row] = b[i * 128 + o] + red[0];
}

__global__ __launch_bounds__(128) void fold_post(const float* __restrict__ bn,
                                                 const float* __restrict__ w,
                                                 const float* __restrict__ b,
                                                 short* __restrict__ WB, float* __restrict__ Bc) {
  int blk = blockIdx.x;
  int i = blk >> 8, o = blk & 255;
  const float* bni = bn + i * 1024;
  float s = bni[o] * rsqrtf(bni[768 + o] + 1e-5f);
  int c = threadIdx.x;
  long idx = (long)(i * 256 + o) * 128 + c;
  WB[idx] = f2bf(w[idx] * s);
  if (c == 0) Bc[i * 256 + o] = b[i * 256 + o] * s + bni[256 + o] - bni[512 + o] * s;
}

// time-energy softmaxes: M1[c][d] = colsoftmax (et2s), M2[c][d] = rowsoftmax (et1s)
__global__ __launch_bounds__(128) void et_softmax(const float* __restrict__ Et,
                                                  short* __restrict__ MB) {
  __shared__ float Es[128 * 128];
  int b = blockIdx.x, t = threadIdx.x;
  const float* E = Et + (long)b * 16384;
  for (int i = t; i < 16384; i += 128) Es[i] = E[i];
  __syncthreads();
  short* M1 = MB + (long)b * 16384;
  short* M2 = MB + (long)(4 + b) * 16384;
  float rm = -1e30f;
  for (int j = 0; j < 128; ++j) rm = fmaxf(rm, Es[t * 128 + j]);
  float rs = 0.f;
  for (int j = 0; j < 128; ++j) rs += __expf(Es[t * 128 + j] - rm);
  float ri = 1.0f / rs;
  for (int j = 0; j < 128; ++j) M2[t * 128 + j] = f2bf(__expf(Es[t * 128 + j] - rm) * ri);
  float cm = -1e30f;
  for (int d = 0; d < 128; ++d) cm = fmaxf(cm, Es[d * 128 + t]);
  float cs = 0.f;
  for (int d = 0; d < 128; ++d) cs += __expf(Es[d * 128 + t] - cm);
  float ci = 1.0f / cs;
  for (int d = 0; d < 128; ++d) M1[t * 128 + d] = f2bf(__expf(Es[d * 128 + t] - cm) * ci);
}

// YTF (f32 split-K partials, y^T [n][128]) -> scale by 1/S -> YT bf16
__global__ __launch_bounds__(256) void yreduce(const float* __restrict__ YTF,
                                               const float* __restrict__ CS,
                                               const float* __restrict__ RS,
                                               short* __restrict__ YT) {
  long idx = ((long)blockIdx.x * 256 + threadIdx.x) << 3;  // 8 f32 elems
  long z = idx / 294912;
  long rem = idx - z * 294912;
  int col = (int)(rem >> 7);
  int sel = (int)(z >> 2), b = (int)(z & 3);
  const float* S = sel ? RS : CS;
  float inv = 1.0f / S[b * N_PIX + col];
  float4 v0 = *(const float4*)&YTF[idx];
  float4 v1 = *(const float4*)&YTF[idx + 4];
  bf16x8 o;
  o[0] = f2bf(v0.x * inv); o[1] = f2bf(v0.y * inv);
  o[2] = f2bf(v0.z * inv); o[3] = f2bf(v0.w * inv);
  o[4] = f2bf(v1.x * inv); o[5] = f2bf(v1.y * inv);
  o[6] = f2bf(v1.z * inv); o[7] = f2bf(v1.w * inv);
  *(bf16x8*)&YT[idx] = o;
}

extern "C" void kernel_launch(void* const* d_in, const int* in_sizes, int n_in,
                              void* d_out, int out_size, void* d_ws, size_t ws_size,
                              hipStream_t stream) {
  const float* x1 = (const float*)d_in[0];
  const float* x2 = (const float*)d_in[1];
  const float* bn_pre = (const float*)d_in[2];
  const float* w_pre = (const float*)d_in[3];
  const float* b_pre = (const float*)d_in[4];
  const float* w_post = (const float*)d_in[5];
  const float* b_post = (const float*)d_in[6];
  const float* bn_post = (const float*)d_in[7];
  float* out = (float*)d_out;

  char* W = (char*)d_ws;
  float* BPRE  = (float*)(W + 0);
  float* BPOST = (float*)(W + 2048);
  float* CS    = (float*)(W + 4096);
  float* RS    = (float*)(W + 40960);
  float* ET    = (float*)(W + 77824);
  short* WPREH = (short*)(W + 339968);
  short* WPREL = (short*)(W + 602112);
  short* WPOSTB= (short*)(W + 864256);
  short* MB    = (short*)(W + 995328);
  short* XTH   = (short*)(W + 1257472);
  short* XTL   = (short*)(W + 10694656);
  short* FB    = (short*)(W + 20131840);
  short* FLO   = (short*)(W + 24850432);
  short* FTB   = (short*)(W + 29569024);
  short* FTLO  = (short*)(W + 39006208);
  short* AB    = (short*)(W + 43724800);
  short* YT    = (short*)(W + 48443392);
  short* PT    = (short*)(W + 53161984);
  float* YTF   = (float*)(W + 95629312);

  hipMemsetAsync(ET, 0, 262144, stream);
  hipMemsetAsync(CS, 0, 36864, stream);
  hipMemsetAsync(RS, 0, 36864, stream);
  hipMemsetAsync(YTF, 0, 9437184, stream);
  xcast<<<dim3(72, 8, 8), 256, 0, stream>>>(x1, x2, XTH, XTL);
  fold_pre<<<512, 256, 0, stream>>>(bn_pre, w_pre, b_pre, WPREH, WPREL, BPRE);
  fold_post<<<512, 128, 0, stream>>>(bn_post, w_post, b_post, WPOSTB, BPOST);

  { GArgs g{};  // pre convs (split): F = Wc @ x  -> FB/FLO (theta,phi), FTB/FTLO
    g.a0 = WPREH; g.a1 = WPREH + 65536; g.al0 = WPREL; g.al1 = WPREL + 65536;
    g.sa = 0; g.sal = 0; g.lda = 256; g.lal = 256;
    g.b0 = XTH; g.b1 = XTH + 4L * 2304 * 256; g.bl0 = XTL; g.bl1 = XTL + 4L * 2304 * 256;
    g.sb = 2304L * 256; g.sbl = 2304L * 256; g.ldb = 256; g.lbl = 256;
    g.K = 256; g.ksplit = 1; g.kchunk = 256; g.bt0 = 0; g.bt1 = 0;
    g.o0 = FB; g.o1 = FB + 4L * 128 * 2304; g.so = 128L * 2304;
    g.p0 = FLO; g.p1 = FLO + 4L * 128 * 2304; g.sp = 128L * 2304;
    g.q0 = FTB; g.q1 = FTB + 4L * 2304 * 256; g.sq = 2304L * 256;
    g.u0 = FTLO; g.u1 = FTLO + 4L * 2304 * 128; g.su = 2304L * 128;
    g.aux0 = BPRE; g.aux1 = BPRE + 256; g.saux = 0;
    mgemm<0, 1><<<dim3(18, 2, 8), 256, 0, stream>>>(g); }

  { GArgs g{};  // e_time (split, K-split 36 atomic): Et[c][d] = sum_n th[c,n] ph[d,n]
    g.a0 = g.a1 = FB; g.al0 = g.al1 = FLO;
    g.sa = g.sal = 128L * 2304; g.lda = g.lal = 2304;
    g.b0 = g.b1 = FB + 4L * 128 * 2304; g.bl0 = g.bl1 = FLO + 4L * 128 * 2304;
    g.sb = g.sbl = 128L * 2304; g.ldb = g.lbl = 2304;
    g.K = 2304; g.ksplit = 36; g.kchunk = 64; g.bt0 = 0; g.bt1 = 0;
    g.o0 = g.o1 = ET; g.so = 16384;
    mgemm<1, 1><<<dim3(1, 1, 144), 256, 0, stream>>>(g); }

  et_softmax<<<4, 128, 0, stream>>>(ET, MB);

  { GArgs g{};  // e_space (split): PT[m][n] = exp(E[n][m]); fused CS/RS sums
    g.a0 = g.a1 = FTB + 128; g.al0 = g.al1 = FTLO;
    g.sa = 2304L * 256; g.sal = 2304L * 128; g.lda = 256; g.lal = 128;
    g.b0 = g.b1 = FTB + 4L * 2304 * 256 + 128; g.bl0 = g.bl1 = FTLO + 4L * 2304 * 128;
    g.sb = 2304L * 256; g.sbl = 2304L * 128; g.ldb = 256; g.lbl = 128;
    g.K = 128; g.ksplit = 1; g.kchunk = 128; g.bt0 = 0; g.bt1 = 0;
    g.o0 = g.o1 = PT; g.so = (long)2304 * 2304;
    g.p0 = CS; g.q0 = RS;
    mgemm<2, 1><<<dim3(18, 18, 4), 256, 0, stream>>>(g); }

  { GArgs g{};  // A-gemms: A1 = M1 @ g11, A2 = M2 @ g21  (B = FTB cols 0..127 = g^T)
    g.a0 = MB; g.a1 = MB + 4 * 16384; g.sa = 16384; g.lda = 128;
    g.b0 = FTB; g.b1 = FTB + 4L * 2304 * 256; g.sb = 2304L * 256; g.ldb = 256;
    g.K = 128; g.ksplit = 1; g.kchunk = 128; g.bt0 = 0; g.bt1 = 0;
    g.o0 = AB; g.o1 = AB + 4L * 128 * 2304; g.so = 128L * 2304;
    mgemm<3, 0><<<dim3(18, 1, 8), 256, 0, stream>>>(g); }

  { GArgs g{};  // y-gemms split-K 6: YTF += A @ P(hat); y1: B=PT rows (NT), y2: transpose-stage
    g.a0 = AB; g.a1 = AB + 4L * 128 * 2304; g.sa = 128L * 2304; g.lda = 2304;
    g.b0 = g.b1 = PT; g.sb = (long)2304 * 2304; g.ldb = 2304;
    g.K = 2304; g.ksplit = 6; g.kchunk = 384; g.bt0 = 0; g.bt1 = 1;
    g.o0 = YTF; g.o1 = YTF + 4L * 2304 * 128; g.so = 2304L * 128;
    mgemm<6, 0><<<dim3(18, 1, 48), 256, 0, stream>>>(g); }

  yreduce<<<1152, 256, 0, stream>>>(YTF, CS, RS, YT);

  { GArgs g{};  // post convs: out_i = x_i + Wpost_i @ y_i + bias
    g.a0 = WPOSTB; g.a1 = WPOSTB + 32768; g.sa = 0; g.lda = 128;
    g.b0 = YT; g.b1 = YT + 4L * 2304 * 128; g.sb = 2304L * 128; g.ldb = 128;
    g.K = 128; g.ksplit = 1; g.kchunk = 128; g.bt0 = 0; g.bt1 = 0;
    g.o0 = out; g.o1 = out + 4L * 256 * 2304; g.so = 256L * 2304;
    g.aux0 = BPOST; g.aux1 = BPOST + 256; g.saux = 0;
    g.res0 = x1; g.res1 = x2; g.sres = 256L * 2304;
    mgemm<5, 0><<<dim3(18, 2, 8), 256, 0, stream>>>(g); }
}

// Round 6
// 244.969 us; speedup vs baseline: 1.7933x; 1.7933x over previous
//
#include <hip/hip_runtime.h>
#include <hip/hip_bf16.h>

// SpatiotemporalAttention — bf16 MFMA pipeline, round 5 (resubmit after GPU timeout).
// B=4, C=256, CI=128, N=48*48=2304.
//
// Round-5 changes (counter-driven):
//   y-gemm: split-K 3 with PRIVATE f32 partials (no atomics — R4's cross-XCD
//           atomic ping-pong cost 226MB of HBM writes), yreduce sums+normalizes
//   bt=1 transpose-stage: 4-row b64 interleave (16x fewer LDS writes)
//   e_time: private partials aliased over YTF + ereduce (no atomics/memset)
//   et_softmax: 256 threads, stride-129 LDS (kills 64-way bank conflict)

#define N_PIX 2304
#define NB 4

typedef __attribute__((ext_vector_type(8))) short bf16x8;
typedef __attribute__((ext_vector_type(4))) float f32x4;

__device__ __forceinline__ short f2bf(float f) {
  unsigned u = __float_as_uint(f);
  unsigned r = (u + 0x7fffu + ((u >> 16) & 1u)) >> 16;
  return (short)r;
}
__device__ __forceinline__ float bf2f(short s) {
  return __uint_as_float(((unsigned)(unsigned short)s) << 16);
}
__device__ __forceinline__ int swz(int row, int kc) {
  return kc ^ ((row ^ (row >> 3)) & 7);
}
__device__ __forceinline__ unsigned pk2(short a, short b) {
  return (unsigned)(unsigned short)a | ((unsigned)(unsigned short)b << 16);
}

// ---------------- workspace layout (byte offsets) ----------------
// CS     f32[4*2304]         @ 0         (colsum of P)   \ one memset
// RS     f32[4*2304]         @ 36864     (rowsum of P)   /
// BPRE   f32[512]            @ 73728
// BPOST  f32[512]            @ 75776
// ET     f32[4*128*128]      @ 77824     (written by ereduce, no memset)
// WPREH  bf16[2*256*256]     @ 339968
// WPREL  bf16[2*256*256]     @ 602112
// WPOSTB bf16[2*256*128]     @ 864256
// MB     bf16[2*4*128*128]   @ 995328    (M1 then M2)
// XTH    bf16[2*4*2304*256]  @ 1257472   (x^T hi)
// XTL    bf16[2*4*2304*256]  @ 10694656
// FB     bf16[2*4*128*2304]  @ 20131840  (theta/phi rows, natural)
// FLO    bf16[2*4*128*2304]  @ 24850432
// FTB    bf16[2*4*2304*256]  @ 29569024  (F^T, all rows)
// FTLO   bf16[2*4*2304*128]  @ 39006208  (F^T lo, theta/phi cols)
// AB     bf16[2*4*128*2304]  @ 43724800
// YT     bf16[2*4*2304*128]  @ 48443392  (y^T)
// PT     bf16[4*2304*2304]   @ 53161984  (PT[a][b] = exp(E[b][a]))
// YTF    f32[3*8*2304*128]   @ 95629312  (y split-K partials; earlier in the
//        pipeline the same region holds ETP f32[36*4*128*128] e_time partials)
// total 123,940,864 B (< 124.4 MB proven in round 1)

struct GArgs {
  const short *a0, *a1, *al0, *al1;
  const short *b0, *b1, *bl0, *bl1;
  long sa, sb, sal, sbl;
  int lda, ldb, lal, lbl;
  int K, ksplit, kchunk;
  int bt0, bt1;                       // B stored [K][N] -> transpose-stage
  void *o0, *o1; long so;
  void *p0, *p1; long sp;
  void *q0, *q1; long sq;
  void *u0, *u1; long su;
  const float *aux0, *aux1; long saux;  // bias (EPI0/5)
  const float *res0, *res1; long sres;  // residual (EPI5)
};

// EPI: 0=pre(F_b/F_lo/FT_b/FT_lo + bias)  1=e_time(private f32 partials)
//      2=ESP(exp -> PT, fused CS/RS atomic sums)  3=A(bf16 natural)
//      5=post(f32+bias+resid)  6=y split-K (private f32 partials)
template <int EPI, int SPLIT>
__global__ __launch_bounds__(256) void mgemm(GArgs g) {
  int z = blockIdx.z;
  int pb = z / g.ksplit, ks = z - pb * g.ksplit;
  int sel = pb >> 2, batch = pb & 3;
  const short* A = (sel ? g.a1 : g.a0) + (long)batch * g.sa;
  const short* B = (sel ? g.b1 : g.b0) + (long)batch * g.sb;
  const short* Al = nullptr; const short* Bl = nullptr;
  if (SPLIT) {
    Al = (sel ? g.al1 : g.al0) + (long)batch * g.sal;
    Bl = (sel ? g.bl1 : g.bl0) + (long)batch * g.sbl;
  }
  int bt = sel ? g.bt1 : g.bt0;
  int k0 = ks * g.kchunk, k1 = k0 + g.kchunk;
  int m0 = blockIdx.y << 7, n0 = blockIdx.x << 7;

  __shared__ short As[128 * 64];
  __shared__ short Bs[128 * 64];
  __shared__ short Als[SPLIT ? 128 * 64 : 8];
  __shared__ short Bls[SPLIT ? 128 * 64 : 8];

  int t = threadIdx.x;
  int lane = t & 63, wid = t >> 6;
  int wm = (wid >> 1) << 6, wn = (wid & 1) << 6;
  int l15 = lane & 15, lg = lane >> 4;

  f32x4 acc[4][4];
  #pragma unroll
  for (int i = 0; i < 4; ++i)
    #pragma unroll
    for (int j = 0; j < 4; ++j) acc[i][j] = (f32x4){0.f, 0.f, 0.f, 0.f};

  for (int kt = k0; kt < k1; kt += 64) {
    __syncthreads();
    #pragma unroll
    for (int i = 0; i < 4; ++i) {
      int ch = t + (i << 8);
      int row = ch >> 3, kc = ch & 7;
      int di = (row << 6) + (swz(row, kc) << 3);
      *(bf16x8*)&As[di] = *(const bf16x8*)&A[(long)(m0 + row) * g.lda + kt + (kc << 3)];
      if (SPLIT)
        *(bf16x8*)&Als[di] = *(const bf16x8*)&Al[(long)(m0 + row) * g.lal + kt + (kc << 3)];
    }
    if (!bt) {
      #pragma unroll
      for (int i = 0; i < 4; ++i) {
        int ch = t + (i << 8);
        int row = ch >> 3, kc = ch & 7;
        int di = (row << 6) + (swz(row, kc) << 3);
        *(bf16x8*)&Bs[di] = *(const bf16x8*)&B[(long)(n0 + row) * g.ldb + kt + (kc << 3)];
        if (SPLIT)
          *(bf16x8*)&Bls[di] = *(const bf16x8*)&Bl[(long)(n0 + row) * g.lbl + kt + (kc << 3)];
      }
    } else {
      // B stored [K][N']: 4-row b64 interleave transpose-stage.
      // thread = (kq, nc): loads rows kt+4kq..+3 at cols n0+8nc..+7,
      // writes 8 x b64, each = 4 consecutive k for one n.
      int nc = t & 15, kq = t >> 4;
      const short* Bp = &B[(long)(kt + (kq << 2)) * g.ldb + n0 + (nc << 3)];
      bf16x8 v0 = *(const bf16x8*)&Bp[0];
      bf16x8 v1 = *(const bf16x8*)&Bp[g.ldb];
      bf16x8 v2 = *(const bf16x8*)&Bp[2 * g.ldb];
      bf16x8 v3 = *(const bf16x8*)&Bp[3 * g.ldb];
      int kc = kq >> 1, wof = (kq & 1) << 2;
      #pragma unroll
      for (int e = 0; e < 8; ++e) {
        int rn = (nc << 3) + e;
        uint2 pkk; pkk.x = pk2(v0[e], v1[e]); pkk.y = pk2(v2[e], v3[e]);
        *(uint2*)&Bs[(rn << 6) + (swz(rn, kc) << 3) + wof] = pkk;
      }
    }
    __syncthreads();
    #pragma unroll
    for (int ksub = 0; ksub < 2; ++ksub) {
      int kb = (ksub << 2) + lg;
      bf16x8 ah[4], bh[4], alv[4], blv[4];
      #pragma unroll
      for (int i = 0; i < 4; ++i) {
        int ra = wm + (i << 4) + l15;
        int rb = wn + (i << 4) + l15;
        ah[i] = *(const bf16x8*)&As[(ra << 6) + (swz(ra, kb) << 3)];
        bh[i] = *(const bf16x8*)&Bs[(rb << 6) + (swz(rb, kb) << 3)];
        if (SPLIT) {
          alv[i] = *(const bf16x8*)&Als[(ra << 6) + (swz(ra, kb) << 3)];
          blv[i] = *(const bf16x8*)&Bls[(rb << 6) + (swz(rb, kb) << 3)];
        }
      }
      #pragma unroll
      for (int i = 0; i < 4; ++i)
        #pragma unroll
        for (int j = 0; j < 4; ++j) {
          if (SPLIT) {
            acc[i][j] = __builtin_amdgcn_mfma_f32_16x16x32_bf16(alv[i], bh[j], acc[i][j], 0, 0, 0);
            acc[i][j] = __builtin_amdgcn_mfma_f32_16x16x32_bf16(ah[i], blv[j], acc[i][j], 0, 0, 0);
          }
          acc[i][j] = __builtin_amdgcn_mfma_f32_16x16x32_bf16(ah[i], bh[j], acc[i][j], 0, 0, 0);
        }
    }
  }

  // ---------------- epilogue ----------------
  float rsacc[16];
  if (EPI == 2) {
    #pragma unroll
    for (int q = 0; q < 16; ++q) rsacc[q] = 0.f;
  }
  #pragma unroll
  for (int j = 0; j < 4; ++j) {
    int col = n0 + wn + (j << 4) + l15;
    float csacc = 0.f;
    #pragma unroll
    for (int i = 0; i < 4; ++i) {
      int row0 = m0 + wm + (i << 4) + (lg << 2);
      if (EPI == 0) {
        const float* bias = (sel ? g.aux1 : g.aux0);
        short* FTB_ = (short*)(sel ? g.q1 : g.q0) + (long)batch * g.sq;
        float v[4]; short hh[4];
        #pragma unroll
        for (int r = 0; r < 4; ++r) { v[r] = acc[i][j][r] + bias[row0 + r]; hh[r] = f2bf(v[r]); }
        uint2 pk; pk.x = pk2(hh[0], hh[1]); pk.y = pk2(hh[2], hh[3]);
        *(uint2*)&FTB_[(long)col * 256 + row0] = pk;
        if (row0 >= 128) {
          short* FB_  = (short*)(sel ? g.o1 : g.o0) + (long)batch * g.so;
          short* FLO_ = (short*)(sel ? g.p1 : g.p0) + (long)batch * g.sp;
          short* FTL_ = (short*)(sel ? g.u1 : g.u0) + (long)batch * g.su;
          short ll[4];
          #pragma unroll
          for (int r = 0; r < 4; ++r) {
            ll[r] = f2bf(v[r] - bf2f(hh[r]));
            FB_[(long)(row0 - 128 + r) * N_PIX + col] = hh[r];
            FLO_[(long)(row0 - 128 + r) * N_PIX + col] = ll[r];
          }
          uint2 pl; pl.x = pk2(ll[0], ll[1]); pl.y = pk2(ll[2], ll[3]);
          *(uint2*)&FTL_[(long)col * 128 + (row0 - 128)] = pl;
        }
      } else if (EPI == 1) {
        float* ETP_ = (float*)g.o0 + ((long)ks * 4 + batch) * 16384;
        #pragma unroll
        for (int r = 0; r < 4; ++r) ETP_[(long)(row0 + r) * 128 + col] = acc[i][j][r];
      } else if (EPI == 2) {
        short* PT_ = (short*)g.o0 + (long)batch * g.so;
        short hh[4];
        #pragma unroll
        for (int r = 0; r < 4; ++r) {
          float ev = __expf(acc[i][j][r]);
          hh[r] = f2bf(ev);
          csacc += ev;
          rsacc[(i << 2) + r] += ev;
        }
        uint2 pk; pk.x = pk2(hh[0], hh[1]); pk.y = pk2(hh[2], hh[3]);
        *(uint2*)&PT_[(long)col * N_PIX + row0] = pk;
      } else if (EPI == 3) {
        short* AB_ = (short*)(sel ? g.o1 : g.o0) + (long)batch * g.so;
        #pragma unroll
        for (int r = 0; r < 4; ++r) AB_[(long)(row0 + r) * N_PIX + col] = f2bf(acc[i][j][r]);
      } else if (EPI == 6) {
        float* YTF_ = (float*)g.o0 + ((long)ks * 8 + sel * 4 + batch) * g.so;
        *(f32x4*)&YTF_[(long)col * 128 + row0] = acc[i][j];
      } else {
        float* O_ = (float*)(sel ? g.o1 : g.o0) + (long)batch * g.so;
        const float* bias = (sel ? g.aux1 : g.aux0);
        const float* R_ = (sel ? g.res1 : g.res0) + (long)batch * g.sres;
        #pragma unroll
        for (int r = 0; r < 4; ++r)
          O_[(long)(row0 + r) * N_PIX + col] =
              acc[i][j][r] + bias[row0 + r] + R_[(long)(row0 + r) * N_PIX + col];
      }
    }
    if (EPI == 2) {
      csacc += __shfl_xor(csacc, 16, 64);
      csacc += __shfl_xor(csacc, 32, 64);
      if (lg == 0) {
        float* CSb = (float*)g.p0 + (long)batch * N_PIX;
        atomicAdd(&CSb[col], csacc);
      }
    }
  }
  if (EPI == 2) {
    float* RSb = (float*)g.q0 + (long)batch * N_PIX;
    #pragma unroll
    for (int i = 0; i < 4; ++i)
      #pragma unroll
      for (int r = 0; r < 4; ++r) {
        float v = rsacc[(i << 2) + r];
        v += __shfl_xor(v, 1, 64);
        v += __shfl_xor(v, 2, 64);
        v += __shfl_xor(v, 4, 64);
        v += __shfl_xor(v, 8, 64);
        if (l15 == 0) atomicAdd(&RSb[m0 + wm + (i << 4) + (lg << 2) + r], v);
      }
  }
}

// ---------------- helper kernels ----------------

__global__ __launch_bounds__(256) void xcast(const float* __restrict__ x1,
                                             const float* __restrict__ x2,
                                             short* __restrict__ XH, short* __restrict__ XL) {
  __shared__ float tile[32][33];
  int z = blockIdx.z; int sel = z >> 2, b = z & 3;
  const float* X = (sel ? x2 : x1) + (long)b * 256 * N_PIX;
  long obase = ((long)(sel * 4 + b)) * N_PIX * 256;
  int n0 = blockIdx.x << 5, c0 = blockIdx.y << 5;
  int tx = threadIdx.x & 31, ty = threadIdx.x >> 5;
  #pragma unroll
  for (int i = 0; i < 4; ++i)
    tile[ty + (i << 3)][tx] = X[(long)(c0 + ty + (i << 3)) * N_PIX + n0 + tx];
  __syncthreads();
  #pragma unroll
  for (int i = 0; i < 4; ++i) {
    int n = n0 + ty + (i << 3);
    float v = tile[tx][ty + (i << 3)];
    short h = f2bf(v);
    XH[obase + (long)n * 256 + c0 + tx] = h;
    XL[obase + (long)n * 256 + c0 + tx] = f2bf(v - bf2f(h));
  }
}

__global__ __launch_bounds__(256) void fold_pre(const float* __restrict__ bn,
                                                const float* __restrict__ w,
                                                const float* __restrict__ b,
                                                short* __restrict__ WH, short* __restrict__ WL,
                                                float* __restrict__ Bc) {
  int blk = blockIdx.x;
  int xsel = blk >> 8, row = blk & 255;
  int i = (row < 128) ? xsel : (2 + xsel);
  int o = row & 127;
  int c = threadIdx.x;
  const float* bni = bn + i * 1024;
  float gm = bni[c], be = bni[256 + c], mn = bni[512 + c], vr = bni[768 + c];
  float s = gm * rsqrtf(vr + 1e-5f);
  float tb = be - mn * s;
  float wv = w[(i * 128 + o) * 256 + c];
  float val = wv * s;
  short h = f2bf(val);
  long idx = (long)(xsel * 256 + row) * 256 + c;
  WH[idx] = h;
  WL[idx] = f2bf(val - bf2f(h));
  __shared__ float red[256];
  red[c] = wv * tb;
  __syncthreads();
  for (int off = 128; off > 0; off >>= 1) {
    if (c < off) red[c] += red[c + off];
    __syncthreads();
  }
  if (c == 0) Bc[xsel * 256 + row] = b[i * 128 + o] + red[0];
}

__global__ __launch_bounds__(128) void fold_post(const float* __restrict__ bn,
                                                 const float* __restrict__ w,
                                                 const float* __restrict__ b,
                                                 short* __restrict__ WB, float* __restrict__ Bc) {
  int blk = blockIdx.x;
  int i = blk >> 8, o = blk & 255;
  const float* bni = bn + i * 1024;
  float s = bni[o] * rsqrtf(bni[768 + o] + 1e-5f);
  int c = threadIdx.x;
  long idx = (long)(i * 256 + o) * 128 + c;
  WB[idx] = f2bf(w[idx] * s);
  if (c == 0) Bc[i * 256 + o] = b[i * 256 + o] * s + bni[256 + o] - bni[512 + o] * s;
}

// sum 36 e_time partials -> ET
__global__ __launch_bounds__(256) void ereduce(const float* __restrict__ ETP,
                                               float* __restrict__ ET) {
  int idx = blockIdx.x * 256 + threadIdx.x;  // 65536 total
  int b = idx >> 14, e = idx & 16383;
  float s = 0.f;
  #pragma unroll
  for (int ks = 0; ks < 36; ++ks) s += ETP[((long)ks * 4 + b) * 16384 + e];
  ET[(long)b * 16384 + e] = s;
}

// time-energy softmaxes: M1[c][d] = colsoftmax (et2s), M2[c][d] = rowsoftmax (et1s)
__global__ __launch_bounds__(256) void et_softmax(const float* __restrict__ Et,
                                                  short* __restrict__ MB) {
  __shared__ float Es[128 * 129];
  int b = blockIdx.x, t = threadIdx.x;
  const float* E = Et + (long)b * 16384;
  for (int i = t; i < 16384; i += 256) {
    int r = i >> 7, c = i & 127;
    Es[r * 129 + c] = E[i];
  }
  __syncthreads();
  short* M1 = MB + (long)b * 16384;
  short* M2 = MB + (long)(4 + b) * 16384;
  if (t < 128) {
    float rm = -1e30f;
    for (int j = 0; j < 128; ++j) rm = fmaxf(rm, Es[t * 129 + j]);
    float rs = 0.f;
    for (int j = 0; j < 128; ++j) rs += __expf(Es[t * 129 + j] - rm);
    float ri = 1.0f / rs;
    for (int j = 0; j < 128; ++j) M2[t * 128 + j] = f2bf(__expf(Es[t * 129 + j] - rm) * ri);
  } else {
    int c = t - 128;
    float cm = -1e30f;
    for (int d = 0; d < 128; ++d) cm = fmaxf(cm, Es[d * 129 + c]);
    float cs = 0.f;
    for (int d = 0; d < 128; ++d) cs += __expf(Es[d * 129 + c] - cm);
    float ci = 1.0f / cs;
    for (int d = 0; d < 128; ++d) M1[c * 128 + d] = f2bf(__expf(Es[d * 129 + c] - cm) * ci);
  }
}

// YTF partials (3x) -> sum -> scale 1/S -> YT bf16
__global__ __launch_bounds__(256) void yreduce(const float* __restrict__ YTF,
                                               const float* __restrict__ CS,
                                               const float* __restrict__ RS,
                                               short* __restrict__ YT) {
  const long PSTR = 8L * 2304 * 128;
  long idx = ((long)blockIdx.x * 256 + threadIdx.x) << 3;  // 8 f32 elems
  long z = idx / 294912;
  long rem = idx - z * 294912;
  int col = (int)(rem >> 7);
  int sel = (int)(z >> 2), b = (int)(z & 3);
  const float* S = sel ? RS : CS;
  float inv = 1.0f / S[b * N_PIX + col];
  float4 a0 = *(const float4*)&YTF[idx];
  float4 a1 = *(const float4*)&YTF[idx + 4];
  float4 b0 = *(const float4*)&YTF[PSTR + idx];
  float4 b1 = *(const float4*)&YTF[PSTR + idx + 4];
  float4 c0 = *(const float4*)&YTF[2 * PSTR + idx];
  float4 c1 = *(const float4*)&YTF[2 * PSTR + idx + 4];
  bf16x8 o;
  o[0] = f2bf((a0.x + b0.x + c0.x) * inv); o[1] = f2bf((a0.y + b0.y + c0.y) * inv);
  o[2] = f2bf((a0.z + b0.z + c0.z) * inv); o[3] = f2bf((a0.w + b0.w + c0.w) * inv);
  o[4] = f2bf((a1.x + b1.x + c1.x) * inv); o[5] = f2bf((a1.y + b1.y + c1.y) * inv);
  o[6] = f2bf((a1.z + b1.z + c1.z) * inv); o[7] = f2bf((a1.w + b1.w + c1.w) * inv);
  *(bf16x8*)&YT[idx] = o;
}

extern "C" void kernel_launch(void* const* d_in, const int* in_sizes, int n_in,
                              void* d_out, int out_size, void* d_ws, size_t ws_size,
                              hipStream_t stream) {
  const float* x1 = (const float*)d_in[0];
  const float* x2 = (const float*)d_in[1];
  const float* bn_pre = (const float*)d_in[2];
  const float* w_pre = (const float*)d_in[3];
  const float* b_pre = (const float*)d_in[4];
  const float* w_post = (const float*)d_in[5];
  const float* b_post = (const float*)d_in[6];
  const float* bn_post = (const float*)d_in[7];
  float* out = (float*)d_out;

  char* W = (char*)d_ws;
  float* CS    = (float*)(W + 0);
  float* RS    = (float*)(W + 36864);
  float* BPRE  = (float*)(W + 73728);
  float* BPOST = (float*)(W + 75776);
  float* ET    = (float*)(W + 77824);
  short* WPREH = (short*)(W + 339968);
  short* WPREL = (short*)(W + 602112);
  short* WPOSTB= (short*)(W + 864256);
  short* MB    = (short*)(W + 995328);
  short* XTH   = (short*)(W + 1257472);
  short* XTL   = (short*)(W + 10694656);
  short* FB    = (short*)(W + 20131840);
  short* FLO   = (short*)(W + 24850432);
  short* FTB   = (short*)(W + 29569024);
  short* FTLO  = (short*)(W + 39006208);
  short* AB    = (short*)(W + 43724800);
  short* YT    = (short*)(W + 48443392);
  short* PT    = (short*)(W + 53161984);
  float* YTF   = (float*)(W + 95629312);  // also e_time partials (ETP)

  hipMemsetAsync(CS, 0, 73728, stream);   // CS + RS (adjacent)
  xcast<<<dim3(72, 8, 8), 256, 0, stream>>>(x1, x2, XTH, XTL);
  fold_pre<<<512, 256, 0, stream>>>(bn_pre, w_pre, b_pre, WPREH, WPREL, BPRE);
  fold_post<<<512, 128, 0, stream>>>(bn_post, w_post, b_post, WPOSTB, BPOST);

  { GArgs g{};  // pre convs (split): F = Wc @ x  -> FB/FLO (theta,phi), FTB/FTLO
    g.a0 = WPREH; g.a1 = WPREH + 65536; g.al0 = WPREL; g.al1 = WPREL + 65536;
    g.sa = 0; g.sal = 0; g.lda = 256; g.lal = 256;
    g.b0 = XTH; g.b1 = XTH + 4L * 2304 * 256; g.bl0 = XTL; g.bl1 = XTL + 4L * 2304 * 256;
    g.sb = 2304L * 256; g.sbl = 2304L * 256; g.ldb = 256; g.lbl = 256;
    g.K = 256; g.ksplit = 1; g.kchunk = 256; g.bt0 = 0; g.bt1 = 0;
    g.o0 = FB; g.o1 = FB + 4L * 128 * 2304; g.so = 128L * 2304;
    g.p0 = FLO; g.p1 = FLO + 4L * 128 * 2304; g.sp = 128L * 2304;
    g.q0 = FTB; g.q1 = FTB + 4L * 2304 * 256; g.sq = 2304L * 256;
    g.u0 = FTLO; g.u1 = FTLO + 4L * 2304 * 128; g.su = 2304L * 128;
    g.aux0 = BPRE; g.aux1 = BPRE + 256; g.saux = 0;
    mgemm<0, 1><<<dim3(18, 2, 8), 256, 0, stream>>>(g); }

  { GArgs g{};  // e_time (split, K-split 36, private partials in YTF region)
    g.a0 = g.a1 = FB; g.al0 = g.al1 = FLO;
    g.sa = g.sal = 128L * 2304; g.lda = g.lal = 2304;
    g.b0 = g.b1 = FB + 4L * 128 * 2304; g.bl0 = g.bl1 = FLO + 4L * 128 * 2304;
    g.sb = g.sbl = 128L * 2304; g.ldb = g.lbl = 2304;
    g.K = 2304; g.ksplit = 36; g.kchunk = 64; g.bt0 = 0; g.bt1 = 0;
    g.o0 = g.o1 = YTF; g.so = 16384;
    mgemm<1, 1><<<dim3(1, 1, 144), 256, 0, stream>>>(g); }

  ereduce<<<256, 256, 0, stream>>>(YTF, ET);
  et_softmax<<<4, 256, 0, stream>>>(ET, MB);

  { GArgs g{};  // e_space (split): PT[m][n] = exp(E[n][m]); fused CS/RS sums
    g.a0 = g.a1 = FTB + 128; g.al0 = g.al1 = FTLO;
    g.sa = 2304L * 256; g.sal = 2304L * 128; g.lda = 256; g.lal = 128;
    g.b0 = g.b1 = FTB + 4L * 2304 * 256 + 128; g.bl0 = g.bl1 = FTLO + 4L * 2304 * 128;
    g.sb = 2304L * 256; g.sbl = 2304L * 128; g.ldb = 256; g.lbl = 128;
    g.K = 128; g.ksplit = 1; g.kchunk = 128; g.bt0 = 0; g.bt1 = 0;
    g.o0 = g.o1 = PT; g.so = (long)2304 * 2304;
    g.p0 = CS; g.q0 = RS;
    mgemm<2, 1><<<dim3(18, 18, 4), 256, 0, stream>>>(g); }

  { GArgs g{};  // A-gemms: A1 = M1 @ g11, A2 = M2 @ g21  (B = FTB cols 0..127 = g^T)
    g.a0 = MB; g.a1 = MB + 4 * 16384; g.sa = 16384; g.lda = 128;
    g.b0 = FTB; g.b1 = FTB + 4L * 2304 * 256; g.sb = 2304L * 256; g.ldb = 256;
    g.K = 128; g.ksplit = 1; g.kchunk = 128; g.bt0 = 0; g.bt1 = 0;
    g.o0 = AB; g.o1 = AB + 4L * 128 * 2304; g.so = 128L * 2304;
    mgemm<3, 0><<<dim3(18, 1, 8), 256, 0, stream>>>(g); }

  { GArgs g{};  // y-gemms split-K 3 private: YTF[ks] = A @ P-slices
    g.a0 = AB; g.a1 = AB + 4L * 128 * 2304; g.sa = 128L * 2304; g.lda = 2304;
    g.b0 = g.b1 = PT; g.sb = (long)2304 * 2304; g.ldb = 2304;
    g.K = 2304; g.ksplit = 3; g.kchunk = 768; g.bt0 = 0; g.bt1 = 1;
    g.o0 = g.o1 = YTF; g.so = 2304L * 128;
    mgemm<6, 0><<<dim3(18, 1, 24), 256, 0, stream>>>(g); }

  yreduce<<<1152, 256, 0, stream>>>(YTF, CS, RS, YT);

  { GArgs g{};  // post convs: out_i = x_i + Wpost_i @ y_i + bias
    g.a0 = WPOSTB; g.a1 = WPOSTB + 32768; g.sa = 0; g.lda = 128;
    g.b0 = YT; g.b1 = YT + 4L * 2304 * 128; g.sb = 2304L * 128; g.ldb = 128;
    g.K = 128; g.ksplit = 1; g.kchunk = 128; g.bt0 = 0; g.bt1 = 0;
    g.o0 = out; g.o1 = out + 4L * 256 * 2304; g.so = 256L * 2304;
    g.aux0 = BPOST; g.aux1 = BPOST + 256; g.saux = 0;
    g.res0 = x1; g.res1 = x2; g.sres = 256L * 2304;
    mgemm<5, 0><<<dim3(18, 2, 8), 256, 0, stream>>>(g); }
}

// Round 7
// 238.417 us; speedup vs baseline: 1.8426x; 1.0275x over previous
//
#include <hip/hip_runtime.h>
#include <hip/hip_bf16.h>

// SpatiotemporalAttention — bf16 MFMA pipeline, round 7.
// B=4, C=256, CI=128, N=48*48=2304.
//
// Round-7 changes (counter-driven: e_space latency-bound at 2 blocks/CU):
//   BK=32 for SPLIT kernels -> 32KB LDS (was 64KB), occupancy 2->3+ blocks/CU
//   CS/RS: block-private partials + csrs_reduce (no cross-XCD atomics, no memset)

#define N_PIX 2304
#define NB 4

typedef __attribute__((ext_vector_type(8))) short bf16x8;
typedef __attribute__((ext_vector_type(4))) float f32x4;

__device__ __forceinline__ short f2bf(float f) {
  unsigned u = __float_as_uint(f);
  unsigned r = (u + 0x7fffu + ((u >> 16) & 1u)) >> 16;
  return (short)r;
}
__device__ __forceinline__ float bf2f(short s) {
  return __uint_as_float(((unsigned)(unsigned short)s) << 16);
}
// BK=64: rows stride 128B (32 banks) -> xor over 8 chunks; BK=32: stride 64B -> xor over 4
__device__ __forceinline__ int swzf(int row, int kc, int bk64) {
  return bk64 ? (kc ^ ((row ^ (row >> 3)) & 7)) : ((kc ^ (row >> 1)) & 3);
}
__device__ __forceinline__ unsigned pk2(short a, short b) {
  return (unsigned)(unsigned short)a | ((unsigned)(unsigned short)b << 16);
}

// ---------------- workspace layout (byte offsets) ----------------
// CS     f32[4*2304]         @ 0         (colsum of P, via csrs_reduce)
// RS     f32[4*2304]         @ 36864     (rowsum of P)
// BPRE   f32[512]            @ 73728
// BPOST  f32[512]            @ 75776
// ET     f32[4*128*128]      @ 77824
// WPREH  bf16[2*256*256]     @ 339968
// WPREL  bf16[2*256*256]     @ 602112
// WPOSTB bf16[2*256*128]     @ 864256
// MB     bf16[2*4*128*128]   @ 995328    (M1 then M2)
// XTH    bf16[2*4*2304*256]  @ 1257472   (x^T hi)
// XTL    bf16[2*4*2304*256]  @ 10694656
// FB     bf16[2*4*128*2304]  @ 20131840  (theta/phi rows, natural)
// FLO    bf16[2*4*128*2304]  @ 24850432
// FTB    bf16[2*4*2304*256]  @ 29569024  (F^T, all rows)
// FTLO   bf16[2*4*2304*128]  @ 39006208  (F^T lo, theta/phi cols)
// AB     bf16[2*4*128*2304]  @ 43724800
// YT     bf16[2*4*2304*128]  @ 48443392  (y^T)
// PT     bf16[4*2304*2304]   @ 53161984  (PT[a][b] = exp(E[b][a]))
// YTF    f32[3*8*2304*128]   @ 95629312  (y split-K partials; region time-shared:
//        (1) e_time partials ETP [36*4*128*128] consumed by ereduce,
//        (2) CSP/RSP [18*4*2304]x2 written by e_space, consumed by csrs_reduce,
//        (3) y split-K partials written by y-gemm, consumed by yreduce)
// total 123,940,864 B

struct GArgs {
  const short *a0, *a1, *al0, *al1;
  const short *b0, *b1, *bl0, *bl1;
  long sa, sb, sal, sbl;
  int lda, ldb, lal, lbl;
  int K, ksplit, kchunk;
  int bt0, bt1;                       // B stored [K][N] -> transpose-stage (BK=64 only)
  void *o0, *o1; long so;
  void *p0, *p1; long sp;
  void *q0, *q1; long sq;
  void *u0, *u1; long su;
  const float *aux0, *aux1; long saux;  // bias (EPI0/5)
  const float *res0, *res1; long sres;  // residual (EPI5)
};

// EPI: 0=pre(F_b/F_lo/FT_b/FT_lo + bias)  1=e_time(private f32 partials)
//      2=ESP(exp -> PT, private CS/RS partials)  3=A(bf16 natural)
//      5=post(f32+bias+resid)  6=y split-K (private f32 partials)
template <int EPI, int SPLIT, int BK>
__global__ __launch_bounds__(256) void mgemm(GArgs g) {
  constexpr int NCHS = (BK == 64) ? 3 : 2;   // log2(BK/8): k-chunks of 8 per row
  constexpr int ROWSH = (BK == 64) ? 6 : 5;  // log2(BK): LDS row stride in shorts
  constexpr int BK64 = (BK == 64);

  int z = blockIdx.z;
  int pb = z / g.ksplit, ks = z - pb * g.ksplit;
  int sel = pb >> 2, batch = pb & 3;
  const short* A = (sel ? g.a1 : g.a0) + (long)batch * g.sa;
  const short* B = (sel ? g.b1 : g.b0) + (long)batch * g.sb;
  const short* Al = nullptr; const short* Bl = nullptr;
  if (SPLIT) {
    Al = (sel ? g.al1 : g.al0) + (long)batch * g.sal;
    Bl = (sel ? g.bl1 : g.bl0) + (long)batch * g.sbl;
  }
  int bt = sel ? g.bt1 : g.bt0;
  int k0 = ks * g.kchunk, k1 = k0 + g.kchunk;
  int m0 = blockIdx.y << 7, n0 = blockIdx.x << 7;

  __shared__ short As[128 * BK];
  __shared__ short Bs[128 * BK];
  __shared__ short Als[SPLIT ? 128 * BK : 8];
  __shared__ short Bls[SPLIT ? 128 * BK : 8];

  int t = threadIdx.x;
  int lane = t & 63, wid = t >> 6;
  int wm = (wid >> 1) << 6, wn = (wid & 1) << 6;
  int l15 = lane & 15, lg = lane >> 4;

  f32x4 acc[4][4];
  #pragma unroll
  for (int i = 0; i < 4; ++i)
    #pragma unroll
    for (int j = 0; j < 4; ++j) acc[i][j] = (f32x4){0.f, 0.f, 0.f, 0.f};

  for (int kt = k0; kt < k1; kt += BK) {
    __syncthreads();
    #pragma unroll
    for (int i = 0; i < BK / 16; ++i) {
      int ch = t + (i << 8);
      int row = ch >> NCHS, kc = ch & ((BK >> 3) - 1);
      int di = (row << ROWSH) + (swzf(row, kc, BK64) << 3);
      *(bf16x8*)&As[di] = *(const bf16x8*)&A[(long)(m0 + row) * g.lda + kt + (kc << 3)];
      if (SPLIT)
        *(bf16x8*)&Als[di] = *(const bf16x8*)&Al[(long)(m0 + row) * g.lal + kt + (kc << 3)];
    }
    if (BK64 && bt) {
      // B stored [K][N']: 4-row b64 interleave transpose-stage (BK=64 path only)
      int nc = t & 15, kq = t >> 4;
      const short* Bp = &B[(long)(kt + (kq << 2)) * g.ldb + n0 + (nc << 3)];
      bf16x8 v0 = *(const bf16x8*)&Bp[0];
      bf16x8 v1 = *(const bf16x8*)&Bp[g.ldb];
      bf16x8 v2 = *(const bf16x8*)&Bp[2 * g.ldb];
      bf16x8 v3 = *(const bf16x8*)&Bp[3 * g.ldb];
      int kc = kq >> 1, wof = (kq & 1) << 2;
      #pragma unroll
      for (int e = 0; e < 8; ++e) {
        int rn = (nc << 3) + e;
        uint2 pkk; pkk.x = pk2(v0[e], v1[e]); pkk.y = pk2(v2[e], v3[e]);
        *(uint2*)&Bs[(rn << 6) + (swzf(rn, kc, 1) << 3) + wof] = pkk;
      }
    } else {
      #pragma unroll
      for (int i = 0; i < BK / 16; ++i) {
        int ch = t + (i << 8);
        int row = ch >> NCHS, kc = ch & ((BK >> 3) - 1);
        int di = (row << ROWSH) + (swzf(row, kc, BK64) << 3);
        *(bf16x8*)&Bs[di] = *(const bf16x8*)&B[(long)(n0 + row) * g.ldb + kt + (kc << 3)];
        if (SPLIT)
          *(bf16x8*)&Bls[di] = *(const bf16x8*)&Bl[(long)(n0 + row) * g.lbl + kt + (kc << 3)];
      }
    }
    __syncthreads();
    #pragma unroll
    for (int ksub = 0; ksub < BK / 32; ++ksub) {
      int kb = (ksub << 2) + lg;
      bf16x8 ah[4], bh[4], alv[4], blv[4];
      #pragma unroll
      for (int i = 0; i < 4; ++i) {
        int ra = wm + (i << 4) + l15;
        int rb = wn + (i << 4) + l15;
        ah[i] = *(const bf16x8*)&As[(ra << ROWSH) + (swzf(ra, kb, BK64) << 3)];
        bh[i] = *(const bf16x8*)&Bs[(rb << ROWSH) + (swzf(rb, kb, BK64) << 3)];
        if (SPLIT) {
          alv[i] = *(const bf16x8*)&Als[(ra << ROWSH) + (swzf(ra, kb, BK64) << 3)];
          blv[i] = *(const bf16x8*)&Bls[(rb << ROWSH) + (swzf(rb, kb, BK64) << 3)];
        }
      }
      #pragma unroll
      for (int i = 0; i < 4; ++i)
        #pragma unroll
        for (int j = 0; j < 4; ++j) {
          if (SPLIT) {
            acc[i][j] = __builtin_amdgcn_mfma_f32_16x16x32_bf16(alv[i], bh[j], acc[i][j], 0, 0, 0);
            acc[i][j] = __builtin_amdgcn_mfma_f32_16x16x32_bf16(ah[i], blv[j], acc[i][j], 0, 0, 0);
          }
          acc[i][j] = __builtin_amdgcn_mfma_f32_16x16x32_bf16(ah[i], bh[j], acc[i][j], 0, 0, 0);
        }
    }
  }

  // ---------------- epilogue ----------------
  float rsacc[16];
  float cs4[4];
  if (EPI == 2) {
    #pragma unroll
    for (int q = 0; q < 16; ++q) rsacc[q] = 0.f;
  }
  #pragma unroll
  for (int j = 0; j < 4; ++j) {
    int col = n0 + wn + (j << 4) + l15;
    float csacc = 0.f;
    #pragma unroll
    for (int i = 0; i < 4; ++i) {
      int row0 = m0 + wm + (i << 4) + (lg << 2);
      if (EPI == 0) {
        const float* bias = (sel ? g.aux1 : g.aux0);
        short* FTB_ = (short*)(sel ? g.q1 : g.q0) + (long)batch * g.sq;
        float v[4]; short hh[4];
        #pragma unroll
        for (int r = 0; r < 4; ++r) { v[r] = acc[i][j][r] + bias[row0 + r]; hh[r] = f2bf(v[r]); }
        uint2 pk; pk.x = pk2(hh[0], hh[1]); pk.y = pk2(hh[2], hh[3]);
        *(uint2*)&FTB_[(long)col * 256 + row0] = pk;
        if (row0 >= 128) {
          short* FB_  = (short*)(sel ? g.o1 : g.o0) + (long)batch * g.so;
          short* FLO_ = (short*)(sel ? g.p1 : g.p0) + (long)batch * g.sp;
          short* FTL_ = (short*)(sel ? g.u1 : g.u0) + (long)batch * g.su;
          short ll[4];
          #pragma unroll
          for (int r = 0; r < 4; ++r) {
            ll[r] = f2bf(v[r] - bf2f(hh[r]));
            FB_[(long)(row0 - 128 + r) * N_PIX + col] = hh[r];
            FLO_[(long)(row0 - 128 + r) * N_PIX + col] = ll[r];
          }
          uint2 pl; pl.x = pk2(ll[0], ll[1]); pl.y = pk2(ll[2], ll[3]);
          *(uint2*)&FTL_[(long)col * 128 + (row0 - 128)] = pl;
        }
      } else if (EPI == 1) {
        float* ETP_ = (float*)g.o0 + ((long)ks * 4 + batch) * 16384;
        #pragma unroll
        for (int r = 0; r < 4; ++r) ETP_[(long)(row0 + r) * 128 + col] = acc[i][j][r];
      } else if (EPI == 2) {
        short* PT_ = (short*)g.o0 + (long)batch * g.so;
        short hh[4];
        #pragma unroll
        for (int r = 0; r < 4; ++r) {
          float ev = __expf(acc[i][j][r]);
          hh[r] = f2bf(ev);
          csacc += ev;
          rsacc[(i << 2) + r] += ev;
        }
        uint2 pk; pk.x = pk2(hh[0], hh[1]); pk.y = pk2(hh[2], hh[3]);
        *(uint2*)&PT_[(long)col * N_PIX + row0] = pk;
      } else if (EPI == 3) {
        short* AB_ = (short*)(sel ? g.o1 : g.o0) + (long)batch * g.so;
        #pragma unroll
        for (int r = 0; r < 4; ++r) AB_[(long)(row0 + r) * N_PIX + col] = f2bf(acc[i][j][r]);
      } else if (EPI == 6) {
        float* YTF_ = (float*)g.o0 + ((long)ks * 8 + sel * 4 + batch) * g.so;
        *(f32x4*)&YTF_[(long)col * 128 + row0] = acc[i][j];
      } else {
        float* O_ = (float*)(sel ? g.o1 : g.o0) + (long)batch * g.so;
        const float* bias = (sel ? g.aux1 : g.aux0);
        const float* R_ = (sel ? g.res1 : g.res0) + (long)batch * g.sres;
        #pragma unroll
        for (int r = 0; r < 4; ++r)
          O_[(long)(row0 + r) * N_PIX + col] =
              acc[i][j][r] + bias[row0 + r] + R_[(long)(row0 + r) * N_PIX + col];
      }
    }
    if (EPI == 2) {
      // col-sum over this block's 128 rows: reduce across lg then across row-halves (LDS)
      csacc += __shfl_xor(csacc, 16, 64);
      csacc += __shfl_xor(csacc, 32, 64);
      cs4[j] = csacc;
    }
  }
  if (EPI == 2) {
    #pragma unroll
    for (int i = 0; i < 4; ++i)
      #pragma unroll
      for (int r = 0; r < 4; ++r) {
        float v = rsacc[(i << 2) + r];
        v += __shfl_xor(v, 1, 64);
        v += __shfl_xor(v, 2, 64);
        v += __shfl_xor(v, 4, 64);
        v += __shfl_xor(v, 8, 64);
        rsacc[(i << 2) + r] = v;
      }
    __syncthreads();                       // MFMA LDS reads done; reuse As/Bs as f32 scratch
    float* scr = (float*)&As[0];           // [rowhalf][128 cols]
    float* scr2 = (float*)&Bs[0];          // [colhalf][128 rows]
    int rowhalf = wid >> 1, colhalf = wid & 1;
    if (lg == 0) {
      #pragma unroll
      for (int j = 0; j < 4; ++j) scr[rowhalf * 128 + wn + (j << 4) + l15] = cs4[j];
    }
    if (l15 == 0) {
      #pragma unroll
      for (int i = 0; i < 4; ++i)
        #pragma unroll
        for (int r = 0; r < 4; ++r)
          scr2[colhalf * 128 + wm + (i << 4) + (lg << 2) + r] = rsacc[(i << 2) + r];
    }
    __syncthreads();
    if (t < 128) {
      float* CSP_ = (float*)g.p0 + ((long)blockIdx.y * 4 + batch) * N_PIX;
      CSP_[n0 + t] = scr[t] + scr[128 + t];
    } else {
      int lr = t - 128;
      float* RSP_ = (float*)g.q0 + ((long)blockIdx.x * 4 + batch) * N_PIX;
      RSP_[m0 + lr] = scr2[lr] + scr2[128 + lr];
    }
  }
}

// ---------------- helper kernels ----------------

__global__ __launch_bounds__(256) void xcast(const float* __restrict__ x1,
                                             const float* __restrict__ x2,
                                             short* __restrict__ XH, short* __restrict__ XL) {
  __shared__ float tile[32][33];
  int z = blockIdx.z; int sel = z >> 2, b = z & 3;
  const float* X = (sel ? x2 : x1) + (long)b * 256 * N_PIX;
  long obase = ((long)(sel * 4 + b)) * N_PIX * 256;
  int n0 = blockIdx.x << 5, c0 = blockIdx.y << 5;
  int tx = threadIdx.x & 31, ty = threadIdx.x >> 5;
  #pragma unroll
  for (int i = 0; i < 4; ++i)
    tile[ty + (i << 3)][tx] = X[(long)(c0 + ty + (i << 3)) * N_PIX + n0 + tx];
  __syncthreads();
  #pragma unroll
  for (int i = 0; i < 4; ++i) {
    int n = n0 + ty + (i << 3);
    float v = tile[tx][ty + (i << 3)];
    short h = f2bf(v);
    XH[obase + (long)n * 256 + c0 + tx] = h;
    XL[obase + (long)n * 256 + c0 + tx] = f2bf(v - bf2f(h));
  }
}

__global__ __launch_bounds__(256) void fold_pre(const float* __restrict__ bn,
                                                const float* __restrict__ w,
                                                const float* __restrict__ b,
                                                short* __restrict__ WH, short* __restrict__ WL,
                                                float* __restrict__ Bc) {
  int blk = blockIdx.x;
  int xsel = blk >> 8, row = blk & 255;
  int i = (row < 128) ? xsel : (2 + xsel);
  int o = row & 127;
  int c = threadIdx.x;
  const float* bni = bn + i * 1024;
  float gm = bni[c], be = bni[256 + c], mn = bni[512 + c], vr = bni[768 + c];
  float s = gm * rsqrtf(vr + 1e-5f);
  float tb = be - mn * s;
  float wv = w[(i * 128 + o) * 256 + c];
  float val = wv * s;
  short h = f2bf(val);
  long idx = (long)(xsel * 256 + row) * 256 + c;
  WH[idx] = h;
  WL[idx] = f2bf(val - bf2f(h));
  __shared__ float red[256];
  red[c] = wv * tb;
  __syncthreads();
  for (int off = 128; off > 0; off >>= 1) {
    if (c < off) red[c] += red[c + off];
    __syncthreads();
  }
  if (c == 0) Bc[xsel * 256 + row] = b[i * 128 + o] + red[0];
}

__global__ __launch_bounds__(128) void fold_post(const float* __restrict__ bn,
                                                 const float* __restrict__ w,
                                                 const float* __restrict__ b,
                                                 short* __restrict__ WB, float* __restrict__ Bc) {
  int blk = blockIdx.x;
  int i = blk >> 8, o = blk & 255;
  const float* bni = bn + i * 1024;
  float s = bni[o] * rsqrtf(bni[768 + o] + 1e-5f);
  int c = threadIdx.x;
  long idx = (long)(i * 256 + o) * 128 + c;
  WB[idx] = f2bf(w[idx] * s);
  if (c == 0) Bc[i * 256 + o] = b[i * 256 + o] * s + bni[256 + o] - bni[512 + o] * s;
}

// sum 36 e_time partials -> ET
__global__ __launch_bounds__(256) void ereduce(const float* __restrict__ ETP,
                                               float* __restrict__ ET) {
  int idx = blockIdx.x * 256 + threadIdx.x;  // 65536 total
  int b = idx >> 14, e = idx & 16383;
  float s = 0.f;
  #pragma unroll
  for (int ks = 0; ks < 36; ++ks) s += ETP[((long)ks * 4 + b) * 16384 + e];
  ET[(long)b * 16384 + e] = s;
}

// time-energy softmaxes: M1[c][d] = colsoftmax (et2s), M2[c][d] = rowsoftmax (et1s)
__global__ __launch_bounds__(256) void et_softmax(const float* __restrict__ Et,
                                                  short* __restrict__ MB) {
  __shared__ float Es[128 * 129];
  int b = blockIdx.x, t = threadIdx.x;
  const float* E = Et + (long)b * 16384;
  for (int i = t; i < 16384; i += 256) {
    int r = i >> 7, c = i & 127;
    Es[r * 129 + c] = E[i];
  }
  __syncthreads();
  short* M1 = MB + (long)b * 16384;
  short* M2 = MB + (long)(4 + b) * 16384;
  if (t < 128) {
    float rm = -1e30f;
    for (int j = 0; j < 128; ++j) rm = fmaxf(rm, Es[t * 129 + j]);
    float rs = 0.f;
    for (int j = 0; j < 128; ++j) rs += __expf(Es[t * 129 + j] - rm);
    float ri = 1.0f / rs;
    for (int j = 0; j < 128; ++j) M2[t * 128 + j] = f2bf(__expf(Es[t * 129 + j] - rm) * ri);
  } else {
    int c = t - 128;
    float cm = -1e30f;
    for (int d = 0; d < 128; ++d) cm = fmaxf(cm, Es[d * 129 + c]);
    float cs = 0.f;
    for (int d = 0; d < 128; ++d) cs += __expf(Es[d * 129 + c] - cm);
    float ci = 1.0f / cs;
    for (int d = 0; d < 128; ++d) M1[c * 128 + d] = f2bf(__expf(Es[d * 129 + c] - cm) * ci);
  }
}

// CSP/RSP 18-way partial sums -> CS, RS
__global__ __launch_bounds__(256) void csrs_reduce(const float* __restrict__ CSP,
                                                   const float* __restrict__ RSP,
                                                   float* __restrict__ CS,
                                                   float* __restrict__ RS) {
  int idx = blockIdx.x * 256 + threadIdx.x;  // 2*4*2304 = 18432
  int which = idx / 9216;
  int rem = idx - which * 9216;
  int b = rem / N_PIX, col = rem - b * N_PIX;
  const float* P = which ? RSP : CSP;
  float s = 0.f;
  #pragma unroll
  for (int k = 0; k < 18; ++k) s += P[((long)k * 4 + b) * N_PIX + col];
  (which ? RS : CS)[b * N_PIX + col] = s;
}

// YTF partials (3x) -> sum -> scale 1/S -> YT bf16
__global__ __launch_bounds__(256) void yreduce(const float* __restrict__ YTF,
                                               const float* __restrict__ CS,
                                               const float* __restrict__ RS,
                                               short* __restrict__ YT) {
  const long PSTR = 8L * 2304 * 128;
  long idx = ((long)blockIdx.x * 256 + threadIdx.x) << 3;  // 8 f32 elems
  long z = idx / 294912;
  long rem = idx - z * 294912;
  int col = (int)(rem >> 7);
  int sel = (int)(z >> 2), b = (int)(z & 3);
  const float* S = sel ? RS : CS;
  float inv = 1.0f / S[b * N_PIX + col];
  float4 a0 = *(const float4*)&YTF[idx];
  float4 a1 = *(const float4*)&YTF[idx + 4];
  float4 b0 = *(const float4*)&YTF[PSTR + idx];
  float4 b1 = *(const float4*)&YTF[PSTR + idx + 4];
  float4 c0 = *(const float4*)&YTF[2 * PSTR + idx];
  float4 c1 = *(const float4*)&YTF[2 * PSTR + idx + 4];
  bf16x8 o;
  o[0] = f2bf((a0.x + b0.x + c0.x) * inv); o[1] = f2bf((a0.y + b0.y + c0.y) * inv);
  o[2] = f2bf((a0.z + b0.z + c0.z) * inv); o[3] = f2bf((a0.w + b0.w + c0.w) * inv);
  o[4] = f2bf((a1.x + b1.x + c1.x) * inv); o[5] = f2bf((a1.y + b1.y + c1.y) * inv);
  o[6] = f2bf((a1.z + b1.z + c1.z) * inv); o[7] = f2bf((a1.w + b1.w + c1.w) * inv);
  *(bf16x8*)&YT[idx] = o;
}

extern "C" void kernel_launch(void* const* d_in, const int* in_sizes, int n_in,
                              void* d_out, int out_size, void* d_ws, size_t ws_size,
                              hipStream_t stream) {
  const float* x1 = (const float*)d_in[0];
  const float* x2 = (const float*)d_in[1];
  const float* bn_pre = (const float*)d_in[2];
  const float* w_pre = (const float*)d_in[3];
  const float* b_pre = (const float*)d_in[4];
  const float* w_post = (const float*)d_in[5];
  const float* b_post = (const float*)d_in[6];
  const float* bn_post = (const float*)d_in[7];
  float* out = (float*)d_out;

  char* W = (char*)d_ws;
  float* CS    = (float*)(W + 0);
  float* RS    = (float*)(W + 36864);
  float* BPRE  = (float*)(W + 73728);
  float* BPOST = (float*)(W + 75776);
  float* ET    = (float*)(W + 77824);
  short* WPREH = (short*)(W + 339968);
  short* WPREL = (short*)(W + 602112);
  short* WPOSTB= (short*)(W + 864256);
  short* MB    = (short*)(W + 995328);
  short* XTH   = (short*)(W + 1257472);
  short* XTL   = (short*)(W + 10694656);
  short* FB    = (short*)(W + 20131840);
  short* FLO   = (short*)(W + 24850432);
  short* FTB   = (short*)(W + 29569024);
  short* FTLO  = (short*)(W + 39006208);
  short* AB    = (short*)(W + 43724800);
  short* YT    = (short*)(W + 48443392);
  short* PT    = (short*)(W + 53161984);
  float* YTF   = (float*)(W + 95629312);  // time-shared: ETP, then CSP/RSP, then y partials
  float* CSP   = (float*)(W + 95629312);
  float* RSP   = (float*)(W + 95629312 + 663552);

  xcast<<<dim3(72, 8, 8), 256, 0, stream>>>(x1, x2, XTH, XTL);
  fold_pre<<<512, 256, 0, stream>>>(bn_pre, w_pre, b_pre, WPREH, WPREL, BPRE);
  fold_post<<<512, 128, 0, stream>>>(bn_post, w_post, b_post, WPOSTB, BPOST);

  { GArgs g{};  // pre convs (split, BK=32): F = Wc @ x -> FB/FLO (theta,phi), FTB/FTLO
    g.a0 = WPREH; g.a1 = WPREH + 65536; g.al0 = WPREL; g.al1 = WPREL + 65536;
    g.sa = 0; g.sal = 0; g.lda = 256; g.lal = 256;
    g.b0 = XTH; g.b1 = XTH + 4L * 2304 * 256; g.bl0 = XTL; g.bl1 = XTL + 4L * 2304 * 256;
    g.sb = 2304L * 256; g.sbl = 2304L * 256; g.ldb = 256; g.lbl = 256;
    g.K = 256; g.ksplit = 1; g.kchunk = 256; g.bt0 = 0; g.bt1 = 0;
    g.o0 = FB; g.o1 = FB + 4L * 128 * 2304; g.so = 128L * 2304;
    g.p0 = FLO; g.p1 = FLO + 4L * 128 * 2304; g.sp = 128L * 2304;
    g.q0 = FTB; g.q1 = FTB + 4L * 2304 * 256; g.sq = 2304L * 256;
    g.u0 = FTLO; g.u1 = FTLO + 4L * 2304 * 128; g.su = 2304L * 128;
    g.aux0 = BPRE; g.aux1 = BPRE + 256; g.saux = 0;
    mgemm<0, 1, 32><<<dim3(18, 2, 8), 256, 0, stream>>>(g); }

  { GArgs g{};  // e_time (split, BK=32, K-split 36, private partials in YTF region)
    g.a0 = g.a1 = FB; g.al0 = g.al1 = FLO;
    g.sa = g.sal = 128L * 2304; g.lda = g.lal = 2304;
    g.b0 = g.b1 = FB + 4L * 128 * 2304; g.bl0 = g.bl1 = FLO + 4L * 128 * 2304;
    g.sb = g.sbl = 128L * 2304; g.ldb = g.lbl = 2304;
    g.K = 2304; g.ksplit = 36; g.kchunk = 64; g.bt0 = 0; g.bt1 = 0;
    g.o0 = g.o1 = YTF; g.so = 16384;
    mgemm<1, 1, 32><<<dim3(1, 1, 144), 256, 0, stream>>>(g); }

  ereduce<<<256, 256, 0, stream>>>(YTF, ET);
  et_softmax<<<4, 256, 0, stream>>>(ET, MB);

  { GArgs g{};  // e_space (split, BK=32): PT[m][n] = exp(E[n][m]); private CS/RS partials
    g.a0 = g.a1 = FTB + 128; g.al0 = g.al1 = FTLO;
    g.sa = 2304L * 256; g.sal = 2304L * 128; g.lda = 256; g.lal = 128;
    g.b0 = g.b1 = FTB + 4L * 2304 * 256 + 128; g.bl0 = g.bl1 = FTLO + 4L * 2304 * 128;
    g.sb = 2304L * 256; g.sbl = 2304L * 128; g.ldb = 256; g.lbl = 128;
    g.K = 128; g.ksplit = 1; g.kchunk = 128; g.bt0 = 0; g.bt1 = 0;
    g.o0 = g.o1 = PT; g.so = (long)2304 * 2304;
    g.p0 = CSP; g.q0 = RSP;
    mgemm<2, 1, 32><<<dim3(18, 18, 4), 256, 0, stream>>>(g); }

  csrs_reduce<<<72, 256, 0, stream>>>(CSP, RSP, CS, RS);

  { GArgs g{};  // A-gemms: A1 = M1 @ g11, A2 = M2 @ g21  (B = FTB cols 0..127 = g^T)
    g.a0 = MB; g.a1 = MB + 4 * 16384; g.sa = 16384; g.lda = 128;
    g.b0 = FTB; g.b1 = FTB + 4L * 2304 * 256; g.sb = 2304L * 256; g.ldb = 256;
    g.K = 128; g.ksplit = 1; g.kchunk = 128; g.bt0 = 0; g.bt1 = 0;
    g.o0 = AB; g.o1 = AB + 4L * 128 * 2304; g.so = 128L * 2304;
    mgemm<3, 0, 64><<<dim3(18, 1, 8), 256, 0, stream>>>(g); }

  { GArgs g{};  // y-gemms split-K 3 private: YTF[ks] = A @ P-slices
    g.a0 = AB; g.a1 = AB + 4L * 128 * 2304; g.sa = 128L * 2304; g.lda = 2304;
    g.b0 = g.b1 = PT; g.sb = (long)2304 * 2304; g.ldb = 2304;
    g.K = 2304; g.ksplit = 3; g.kchunk = 768; g.bt0 = 0; g.bt1 = 1;
    g.o0 = g.o1 = YTF; g.so = 2304L * 128;
    mgemm<6, 0, 64><<<dim3(18, 1, 24), 256, 0, stream>>>(g); }

  yreduce<<<1152, 256, 0, stream>>>(YTF, CS, RS, YT);

  { GArgs g{};  // post convs: out_i = x_i + Wpost_i @ y_i + bias
    g.a0 = WPOSTB; g.a1 = WPOSTB + 32768; g.sa = 0; g.lda = 128;
    g.b0 = YT; g.b1 = YT + 4L * 2304 * 128; g.sb = 2304L * 128; g.ldb = 128;
    g.K = 128; g.ksplit = 1; g.kchunk = 128; g.bt0 = 0; g.bt1 = 0;
    g.o0 = out; g.o1 = out + 4L * 256 * 2304; g.so = 256L * 2304;
    g.aux0 = BPOST; g.aux1 = BPOST + 256; g.saux = 0;
    g.res0 = x1; g.res1 = x2; g.sres = 256L * 2304;
    mgemm<5, 0, 64><<<dim3(18, 2, 8), 256, 0, stream>>>(g); }
}

// Round 8
// 235.321 us; speedup vs baseline: 1.8668x; 1.0132x over previous
//
#include <hip/hip_runtime.h>
#include <hip/hip_bf16.h>

// SpatiotemporalAttention — bf16 MFMA pipeline, round 8.
// B=4, C=256, CI=128, N=48*48=2304.
//
// Round-8 changes (counter-driven: all mgemms stage-latency-bound):
//   global_load_lds width=16 staging (linear LDS dest + pre-swizzled global src;
//   XOR swizzle is self-inverse, preserved 64B coalescing groups)
//   e_space epilogue: PT store transposed through LDS -> coalesced 256B stores
//   (was 16x scattered 8B stores/thread)

#define N_PIX 2304
#define NB 4

typedef __attribute__((ext_vector_type(8))) short bf16x8;
typedef __attribute__((ext_vector_type(4))) float f32x4;

__device__ __forceinline__ short f2bf(float f) {
  unsigned u = __float_as_uint(f);
  unsigned r = (u + 0x7fffu + ((u >> 16) & 1u)) >> 16;
  return (short)r;
}
__device__ __forceinline__ float bf2f(short s) {
  return __uint_as_float(((unsigned)(unsigned short)s) << 16);
}
// BK=64: rows stride 128B -> xor over 8 chunks; BK=32: stride 64B -> xor over 4.
// Both are XOR by f(row): self-inverse.
__device__ __forceinline__ int swzf(int row, int kc, int bk64) {
  return bk64 ? (kc ^ ((row ^ (row >> 3)) & 7)) : ((kc ^ (row >> 1)) & 3);
}
__device__ __forceinline__ unsigned pk2(short a, short b) {
  return (unsigned)(unsigned short)a | ((unsigned)(unsigned short)b << 16);
}
__device__ __forceinline__ void gll16(const short* g, short* l) {
  __builtin_amdgcn_global_load_lds((const __attribute__((address_space(1))) void*)g,
                                   (__attribute__((address_space(3))) void*)l, 16, 0, 0);
}

// ---------------- workspace layout (byte offsets) ----------------
// CS     f32[4*2304]         @ 0
// RS     f32[4*2304]         @ 36864
// BPRE   f32[512]            @ 73728
// BPOST  f32[512]            @ 75776
// ET     f32[4*128*128]      @ 77824
// WPREH  bf16[2*256*256]     @ 339968
// WPREL  bf16[2*256*256]     @ 602112
// WPOSTB bf16[2*256*128]     @ 864256
// MB     bf16[2*4*128*128]   @ 995328
// XTH    bf16[2*4*2304*256]  @ 1257472
// XTL    bf16[2*4*2304*256]  @ 10694656
// FB     bf16[2*4*128*2304]  @ 20131840
// FLO    bf16[2*4*128*2304]  @ 24850432
// FTB    bf16[2*4*2304*256]  @ 29569024
// FTLO   bf16[2*4*2304*128]  @ 39006208
// AB     bf16[2*4*128*2304]  @ 43724800
// YT     bf16[2*4*2304*128]  @ 48443392
// PT     bf16[4*2304*2304]   @ 53161984
// YTF    f32[3*8*2304*128]   @ 95629312  (time-shared: ETP, CSP/RSP, y partials)
// total 123,940,864 B

struct GArgs {
  const short *a0, *a1, *al0, *al1;
  const short *b0, *b1, *bl0, *bl1;
  long sa, sb, sal, sbl;
  int lda, ldb, lal, lbl;
  int K, ksplit, kchunk;
  int bt0, bt1;
  void *o0, *o1; long so;
  void *p0, *p1; long sp;
  void *q0, *q1; long sq;
  void *u0, *u1; long su;
  const float *aux0, *aux1; long saux;
  const float *res0, *res1; long sres;
};

// EPI: 0=pre  1=e_time(private partials)  2=ESP(exp->PT via LDS transpose, CS/RS partials)
//      3=A    5=post(f32+bias+resid)      6=y split-K (private partials)
template <int EPI, int SPLIT, int BK>
__global__ __launch_bounds__(256) void mgemm(GArgs g) {
  constexpr int NCHS = (BK == 64) ? 3 : 2;
  constexpr int ROWSH = (BK == 64) ? 6 : 5;
  constexpr int BK64 = (BK == 64);
  constexpr int NT = SPLIT ? 4 : 2;

  int z = blockIdx.z;
  int pb = z / g.ksplit, ks = z - pb * g.ksplit;
  int sel = pb >> 2, batch = pb & 3;
  const short* A = (sel ? g.a1 : g.a0) + (long)batch * g.sa;
  const short* B = (sel ? g.b1 : g.b0) + (long)batch * g.sb;
  const short* Al = nullptr; const short* Bl = nullptr;
  if (SPLIT) {
    Al = (sel ? g.al1 : g.al0) + (long)batch * g.sal;
    Bl = (sel ? g.bl1 : g.bl0) + (long)batch * g.sbl;
  }
  int bt = sel ? g.bt1 : g.bt0;
  int k0 = ks * g.kchunk, k1 = k0 + g.kchunk;
  int m0 = blockIdx.y << 7, n0 = blockIdx.x << 7;

  __shared__ short SM[NT * 128 * BK];
  short* As = SM;
  short* Bs = SM + 128 * BK;
  short* Als = SM + (SPLIT ? 2 : 0) * 128 * BK;
  short* Bls = SM + (SPLIT ? 3 : 0) * 128 * BK;

  int t = threadIdx.x;
  int lane = t & 63, wid = t >> 6;
  int wm = (wid >> 1) << 6, wn = (wid & 1) << 6;
  int l15 = lane & 15, lg = lane >> 4;

  f32x4 acc[4][4];
  #pragma unroll
  for (int i = 0; i < 4; ++i)
    #pragma unroll
    for (int j = 0; j < 4; ++j) acc[i][j] = (f32x4){0.f, 0.f, 0.f, 0.f};

  for (int kt = k0; kt < k1; kt += BK) {
    __syncthreads();
    // ---- stage A (+Al): async direct-to-LDS, linear dest, pre-swizzled src
    #pragma unroll
    for (int i = 0; i < BK / 16; ++i) {
      int ch = t + (i << 8);
      int row = ch >> NCHS, kc = ch & ((BK >> 3) - 1);
      int kcs = swzf(row, kc, BK64);             // self-inverse
      int lb = (i << 11) + (wid << 9);           // shorts: ch0*8
      gll16(&A[(long)(m0 + row) * g.lda + kt + (kcs << 3)], As + lb);
      if (SPLIT)
        gll16(&Al[(long)(m0 + row) * g.lal + kt + (kcs << 3)], Als + lb);
    }
    // ---- stage B (+Bl)
    if (BK64 && bt) {
      // B stored [K][N']: 4-row b64 interleave transpose-stage (manual path)
      int nc = t & 15, kq = t >> 4;
      const short* Bp = &B[(long)(kt + (kq << 2)) * g.ldb + n0 + (nc << 3)];
      bf16x8 v0 = *(const bf16x8*)&Bp[0];
      bf16x8 v1 = *(const bf16x8*)&Bp[g.ldb];
      bf16x8 v2 = *(const bf16x8*)&Bp[2 * g.ldb];
      bf16x8 v3 = *(const bf16x8*)&Bp[3 * g.ldb];
      int kc = kq >> 1, wof = (kq & 1) << 2;
      #pragma unroll
      for (int e = 0; e < 8; ++e) {
        int rn = (nc << 3) + e;
        uint2 pkk; pkk.x = pk2(v0[e], v1[e]); pkk.y = pk2(v2[e], v3[e]);
        *(uint2*)&Bs[(rn << 6) + (swzf(rn, kc, 1) << 3) + wof] = pkk;
      }
    } else {
      #pragma unroll
      for (int i = 0; i < BK / 16; ++i) {
        int ch = t + (i << 8);
        int row = ch >> NCHS, kc = ch & ((BK >> 3) - 1);
        int kcs = swzf(row, kc, BK64);
        int lb = (i << 11) + (wid << 9);
        gll16(&B[(long)(n0 + row) * g.ldb + kt + (kcs << 3)], Bs + lb);
        if (SPLIT)
          gll16(&Bl[(long)(n0 + row) * g.lbl + kt + (kcs << 3)], Bls + lb);
      }
    }
    __syncthreads();
    #pragma unroll
    for (int ksub = 0; ksub < BK / 32; ++ksub) {
      int kb = (ksub << 2) + lg;
      bf16x8 ah[4], bh[4], alv[4], blv[4];
      #pragma unroll
      for (int i = 0; i < 4; ++i) {
        int ra = wm + (i << 4) + l15;
        int rb = wn + (i << 4) + l15;
        ah[i] = *(const bf16x8*)&As[(ra << ROWSH) + (swzf(ra, kb, BK64) << 3)];
        bh[i] = *(const bf16x8*)&Bs[(rb << ROWSH) + (swzf(rb, kb, BK64) << 3)];
        if (SPLIT) {
          alv[i] = *(const bf16x8*)&Als[(ra << ROWSH) + (swzf(ra, kb, BK64) << 3)];
          blv[i] = *(const bf16x8*)&Bls[(rb << ROWSH) + (swzf(rb, kb, BK64) << 3)];
        }
      }
      #pragma unroll
      for (int i = 0; i < 4; ++i)
        #pragma unroll
        for (int j = 0; j < 4; ++j) {
          if (SPLIT) {
            acc[i][j] = __builtin_amdgcn_mfma_f32_16x16x32_bf16(alv[i], bh[j], acc[i][j], 0, 0, 0);
            acc[i][j] = __builtin_amdgcn_mfma_f32_16x16x32_bf16(ah[i], blv[j], acc[i][j], 0, 0, 0);
          }
          acc[i][j] = __builtin_amdgcn_mfma_f32_16x16x32_bf16(ah[i], bh[j], acc[i][j], 0, 0, 0);
        }
    }
  }

  // ---------------- epilogue ----------------
  if (EPI == 2) {
    // phase 1: exp + pack -> LDS (swizzled 8B units) + cs/rs register accumulate
    float rsacc[16];
    #pragma unroll
    for (int q = 0; q < 16; ++q) rsacc[q] = 0.f;
    float cs4[4];
    __syncthreads();                  // SM free (all MFMA reads drained)
    #pragma unroll
    for (int j = 0; j < 4; ++j) {
      int c = wn + (j << 4) + l15;
      float csacc = 0.f;
      #pragma unroll
      for (int i = 0; i < 4; ++i) {
        short hh[4];
        #pragma unroll
        for (int r = 0; r < 4; ++r) {
          float ev = __expf(acc[i][j][r]);
          hh[r] = f2bf(ev);
          csacc += ev;
          rsacc[(i << 2) + r] += ev;
        }
        uint2 pk; pk.x = pk2(hh[0], hh[1]); pk.y = pk2(hh[2], hh[3]);
        int u8 = (wm >> 2) + (i << 2) + lg;          // 8B unit = 4 rows
        ((uint2*)SM)[(c << 5) + (u8 ^ ((c & 15) << 1))] = pk;
      }
      csacc += __shfl_xor(csacc, 16, 64);
      csacc += __shfl_xor(csacc, 32, 64);
      cs4[j] = csacc;
    }
    #pragma unroll
    for (int i = 0; i < 4; ++i)
      #pragma unroll
      for (int r = 0; r < 4; ++r) {
        float v = rsacc[(i << 2) + r];
        v += __shfl_xor(v, 1, 64);
        v += __shfl_xor(v, 2, 64);
        v += __shfl_xor(v, 4, 64);
        v += __shfl_xor(v, 8, 64);
        rsacc[(i << 2) + r] = v;
      }
    __syncthreads();
    // phase 2: coalesced PT store (256B contiguous per column)
    short* PT_ = (short*)g.o0 + (long)batch * g.so;
    #pragma unroll
    for (int p = 0; p < 8; ++p) {
      int cc = (p << 4) + (t >> 4);
      bf16x8 v = *(bf16x8*)&SM[(cc << 7) + (((t & 15) ^ (cc & 15)) << 3)];
      *(bf16x8*)&PT_[(long)(n0 + cc) * N_PIX + m0 + ((t & 15) << 3)] = v;
    }
    __syncthreads();
    // phase 3: CS/RS block partials via SM scratch
    float* scr = (float*)SM;          // [rowhalf][128 cols]
    float* scr2 = scr + 256;          // [colhalf][128 rows]
    int rowhalf = wid >> 1, colhalf = wid & 1;
    if (lg == 0) {
      #pragma unroll
      for (int j = 0; j < 4; ++j) scr[rowhalf * 128 + wn + (j << 4) + l15] = cs4[j];
    }
    if (l15 == 0) {
      #pragma unroll
      for (int i = 0; i < 4; ++i)
        #pragma unroll
        for (int r = 0; r < 4; ++r)
          scr2[colhalf * 128 + wm + (i << 4) + (lg << 2) + r] = rsacc[(i << 2) + r];
    }
    __syncthreads();
    if (t < 128) {
      float* CSP_ = (float*)g.p0 + ((long)blockIdx.y * 4 + batch) * N_PIX;
      CSP_[n0 + t] = scr[t] + scr[128 + t];
    } else {
      int lr = t - 128;
      float* RSP_ = (float*)g.q0 + ((long)blockIdx.x * 4 + batch) * N_PIX;
      RSP_[m0 + lr] = scr2[lr] + scr2[128 + lr];
    }
    return;
  }

  #pragma unroll
  for (int j = 0; j < 4; ++j) {
    int col = n0 + wn + (j << 4) + l15;
    #pragma unroll
    for (int i = 0; i < 4; ++i) {
      int row0 = m0 + wm + (i << 4) + (lg << 2);
      if (EPI == 0) {
        const float* bias = (sel ? g.aux1 : g.aux0);
        short* FTB_ = (short*)(sel ? g.q1 : g.q0) + (long)batch * g.sq;
        float v[4]; short hh[4];
        #pragma unroll
        for (int r = 0; r < 4; ++r) { v[r] = acc[i][j][r] + bias[row0 + r]; hh[r] = f2bf(v[r]); }
        uint2 pk; pk.x = pk2(hh[0], hh[1]); pk.y = pk2(hh[2], hh[3]);
        *(uint2*)&FTB_[(long)col * 256 + row0] = pk;
        if (row0 >= 128) {
          short* FB_  = (short*)(sel ? g.o1 : g.o0) + (long)batch * g.so;
          short* FLO_ = (short*)(sel ? g.p1 : g.p0) + (long)batch * g.sp;
          short* FTL_ = (short*)(sel ? g.u1 : g.u0) + (long)batch * g.su;
          short ll[4];
          #pragma unroll
          for (int r = 0; r < 4; ++r) {
            ll[r] = f2bf(v[r] - bf2f(hh[r]));
            FB_[(long)(row0 - 128 + r) * N_PIX + col] = hh[r];
            FLO_[(long)(row0 - 128 + r) * N_PIX + col] = ll[r];
          }
          uint2 pl; pl.x = pk2(ll[0], ll[1]); pl.y = pk2(ll[2], ll[3]);
          *(uint2*)&FTL_[(long)col * 128 + (row0 - 128)] = pl;
        }
      } else if (EPI == 1) {
        float* ETP_ = (float*)g.o0 + ((long)ks * 4 + batch) * 16384;
        #pragma unroll
        for (int r = 0; r < 4; ++r) ETP_[(long)(row0 + r) * 128 + col] = acc[i][j][r];
      } else if (EPI == 3) {
        short* AB_ = (short*)(sel ? g.o1 : g.o0) + (long)batch * g.so;
        #pragma unroll
        for (int r = 0; r < 4; ++r) AB_[(long)(row0 + r) * N_PIX + col] = f2bf(acc[i][j][r]);
      } else if (EPI == 6) {
        float* YTF_ = (float*)g.o0 + ((long)ks * 8 + sel * 4 + batch) * g.so;
        *(f32x4*)&YTF_[(long)col * 128 + row0] = acc[i][j];
      } else {
        float* O_ = (float*)(sel ? g.o1 : g.o0) + (long)batch * g.so;
        const float* bias = (sel ? g.aux1 : g.aux0);
        const float* R_ = (sel ? g.res1 : g.res0) + (long)batch * g.sres;
        #pragma unroll
        for (int r = 0; r < 4; ++r)
          O_[(long)(row0 + r) * N_PIX + col] =
              acc[i][j][r] + bias[row0 + r] + R_[(long)(row0 + r) * N_PIX + col];
      }
    }
  }
}

// ---------------- helper kernels ----------------

__global__ __launch_bounds__(256) void xcast(const float* __restrict__ x1,
                                             const float* __restrict__ x2,
                                             short* __restrict__ XH, short* __restrict__ XL) {
  __shared__ float tile[32][33];
  int z = blockIdx.z; int sel = z >> 2, b = z & 3;
  const float* X = (sel ? x2 : x1) + (long)b * 256 * N_PIX;
  long obase = ((long)(sel * 4 + b)) * N_PIX * 256;
  int n0 = blockIdx.x << 5, c0 = blockIdx.y << 5;
  int tx = threadIdx.x & 31, ty = threadIdx.x >> 5;
  #pragma unroll
  for (int i = 0; i < 4; ++i)
    tile[ty + (i << 3)][tx] = X[(long)(c0 + ty + (i << 3)) * N_PIX + n0 + tx];
  __syncthreads();
  #pragma unroll
  for (int i = 0; i < 4; ++i) {
    int n = n0 + ty + (i << 3);
    float v = tile[tx][ty + (i << 3)];
    short h = f2bf(v);
    XH[obase + (long)n * 256 + c0 + tx] = h;
    XL[obase + (long)n * 256 + c0 + tx] = f2bf(v - bf2f(h));
  }
}

__global__ __launch_bounds__(256) void fold_pre(const float* __restrict__ bn,
                                                const float* __restrict__ w,
                                                const float* __restrict__ b,
                                                short* __restrict__ WH, short* __restrict__ WL,
                                                float* __restrict__ Bc) {
  int blk = blockIdx.x;
  int xsel = blk >> 8, row = blk & 255;
  int i = (row < 128) ? xsel : (2 + xsel);
  int o = row & 127;
  int c = threadIdx.x;
  const float* bni = bn + i * 1024;
  float gm = bni[c], be = bni[256 + c], mn = bni[512 + c], vr = bni[768 + c];
  float s = gm * rsqrtf(vr + 1e-5f);
  float tb = be - mn * s;
  float wv = w[(i * 128 + o) * 256 + c];
  float val = wv * s;
  short h = f2bf(val);
  long idx = (long)(xsel * 256 + row) * 256 + c;
  WH[idx] = h;
  WL[idx] = f2bf(val - bf2f(h));
  __shared__ float red[256];
  red[c] = wv * tb;
  __syncthreads();
  for (int off = 128; off > 0; off >>= 1) {
    if (c < off) red[c] += red[c + off];
    __syncthreads();
  }
  if (c == 0) Bc[xsel * 256 + row] = b[i * 128 + o] + red[0];
}

__global__ __launch_bounds__(128) void fold_post(const float* __restrict__ bn,
                                                 const float* __restrict__ w,
                                                 const float* __restrict__ b,
                                                 short* __restrict__ WB, float* __restrict__ Bc) {
  int blk = blockIdx.x;
  int i = blk >> 8, o = blk & 255;
  const float* bni = bn + i * 1024;
  float s = bni[o] * rsqrtf(bni[768 + o] + 1e-5f);
  int c = threadIdx.x;
  long idx = (long)(i * 256 + o) * 128 + c;
  WB[idx] = f2bf(w[idx] * s);
  if (c == 0) Bc[i * 256 + o] = b[i * 256 + o] * s + bni[256 + o] - bni[512 + o] * s;
}

// sum 36 e_time partials -> ET
__global__ __launch_bounds__(256) void ereduce(const float* __restrict__ ETP,
                                               float* __restrict__ ET) {
  int idx = blockIdx.x * 256 + threadIdx.x;  // 65536 total
  int b = idx >> 14, e = idx & 16383;
  float s = 0.f;
  #pragma unroll
  for (int ks = 0; ks < 36; ++ks) s += ETP[((long)ks * 4 + b) * 16384 + e];
  ET[(long)b * 16384 + e] = s;
}

// time-energy softmaxes: M1[c][d] = colsoftmax (et2s), M2[c][d] = rowsoftmax (et1s)
__global__ __launch_bounds__(256) void et_softmax(const float* __restrict__ Et,
                                                  short* __restrict__ MB) {
  __shared__ float Es[128 * 129];
  int b = blockIdx.x, t = threadIdx.x;
  const float* E = Et + (long)b * 16384;
  for (int i = t; i < 16384; i += 256) {
    int r = i >> 7, c = i & 127;
    Es[r * 129 + c] = E[i];
  }
  __syncthreads();
  short* M1 = MB + (long)b * 16384;
  short* M2 = MB + (long)(4 + b) * 16384;
  if (t < 128) {
    float rm = -1e30f;
    for (int j = 0; j < 128; ++j) rm = fmaxf(rm, Es[t * 129 + j]);
    float rs = 0.f;
    for (int j = 0; j < 128; ++j) rs += __expf(Es[t * 129 + j] - rm);
    float ri = 1.0f / rs;
    for (int j = 0; j < 128; ++j) M2[t * 128 + j] = f2bf(__expf(Es[t * 129 + j] - rm) * ri);
  } else {
    int c = t - 128;
    float cm = -1e30f;
    for (int d = 0; d < 128; ++d) cm = fmaxf(cm, Es[d * 129 + c]);
    float cs = 0.f;
    for (int d = 0; d < 128; ++d) cs += __expf(Es[d * 129 + c] - cm);
    float ci = 1.0f / cs;
    for (int d = 0; d < 128; ++d) M1[c * 128 + d] = f2bf(__expf(Es[d * 129 + c] - cm) * ci);
  }
}

// CSP/RSP 18-way partial sums -> CS, RS
__global__ __launch_bounds__(256) void csrs_reduce(const float* __restrict__ CSP,
                                                   const float* __restrict__ RSP,
                                                   float* __restrict__ CS,
                                                   float* __restrict__ RS) {
  int idx = blockIdx.x * 256 + threadIdx.x;  // 18432
  int which = idx / 9216;
  int rem = idx - which * 9216;
  int b = rem / N_PIX, col = rem - b * N_PIX;
  const float* P = which ? RSP : CSP;
  float s = 0.f;
  #pragma unroll
  for (int k = 0; k < 18; ++k) s += P[((long)k * 4 + b) * N_PIX + col];
  (which ? RS : CS)[b * N_PIX + col] = s;
}

// YTF partials (3x) -> sum -> scale 1/S -> YT bf16
__global__ __launch_bounds__(256) void yreduce(const float* __restrict__ YTF,
                                               const float* __restrict__ CS,
                                               const float* __restrict__ RS,
                                               short* __restrict__ YT) {
  const long PSTR = 8L * 2304 * 128;
  long idx = ((long)blockIdx.x * 256 + threadIdx.x) << 3;
  long z = idx / 294912;
  long rem = idx - z * 294912;
  int col = (int)(rem >> 7);
  int sel = (int)(z >> 2), b = (int)(z & 3);
  const float* S = sel ? RS : CS;
  float inv = 1.0f / S[b * N_PIX + col];
  float4 a0 = *(const float4*)&YTF[idx];
  float4 a1 = *(const float4*)&YTF[idx + 4];
  float4 b0 = *(const float4*)&YTF[PSTR + idx];
  float4 b1 = *(const float4*)&YTF[PSTR + idx + 4];
  float4 c0 = *(const float4*)&YTF[2 * PSTR + idx];
  float4 c1 = *(const float4*)&YTF[2 * PSTR + idx + 4];
  bf16x8 o;
  o[0] = f2bf((a0.x + b0.x + c0.x) * inv); o[1] = f2bf((a0.y + b0.y + c0.y) * inv);
  o[2] = f2bf((a0.z + b0.z + c0.z) * inv); o[3] = f2bf((a0.w + b0.w + c0.w) * inv);
  o[4] = f2bf((a1.x + b1.x + c1.x) * inv); o[5] = f2bf((a1.y + b1.y + c1.y) * inv);
  o[6] = f2bf((a1.z + b1.z + c1.z) * inv); o[7] = f2bf((a1.w + b1.w + c1.w) * inv);
  *(bf16x8*)&YT[idx] = o;
}

extern "C" void kernel_launch(void* const* d_in, const int* in_sizes, int n_in,
                              void* d_out, int out_size, void* d_ws, size_t ws_size,
                              hipStream_t stream) {
  const float* x1 = (const float*)d_in[0];
  const float* x2 = (const float*)d_in[1];
  const float* bn_pre = (const float*)d_in[2];
  const float* w_pre = (const float*)d_in[3];
  const float* b_pre = (const float*)d_in[4];
  const float* w_post = (const float*)d_in[5];
  const float* b_post = (const float*)d_in[6];
  const float* bn_post = (const float*)d_in[7];
  float* out = (float*)d_out;

  char* W = (char*)d_ws;
  float* CS    = (float*)(W + 0);
  float* RS    = (float*)(W + 36864);
  float* BPRE  = (float*)(W + 73728);
  float* BPOST = (float*)(W + 75776);
  float* ET    = (float*)(W + 77824);
  short* WPREH = (short*)(W + 339968);
  short* WPREL = (short*)(W + 602112);
  short* WPOSTB= (short*)(W + 864256);
  short* MB    = (short*)(W + 995328);
  short* XTH   = (short*)(W + 1257472);
  short* XTL   = (short*)(W + 10694656);
  short* FB    = (short*)(W + 20131840);
  short* FLO   = (short*)(W + 24850432);
  short* FTB   = (short*)(W + 29569024);
  short* FTLO  = (short*)(W + 39006208);
  short* AB    = (short*)(W + 43724800);
  short* YT    = (short*)(W + 48443392);
  short* PT    = (short*)(W + 53161984);
  float* YTF   = (float*)(W + 95629312);
  float* CSP   = (float*)(W + 95629312);
  float* RSP   = (float*)(W + 95629312 + 663552);

  xcast<<<dim3(72, 8, 8), 256, 0, stream>>>(x1, x2, XTH, XTL);
  fold_pre<<<512, 256, 0, stream>>>(bn_pre, w_pre, b_pre, WPREH, WPREL, BPRE);
  fold_post<<<512, 128, 0, stream>>>(bn_post, w_post, b_post, WPOSTB, BPOST);

  { GArgs g{};  // pre convs (split, BK=32)
    g.a0 = WPREH; g.a1 = WPREH + 65536; g.al0 = WPREL; g.al1 = WPREL + 65536;
    g.sa = 0; g.sal = 0; g.lda = 256; g.lal = 256;
    g.b0 = XTH; g.b1 = XTH + 4L * 2304 * 256; g.bl0 = XTL; g.bl1 = XTL + 4L * 2304 * 256;
    g.sb = 2304L * 256; g.sbl = 2304L * 256; g.ldb = 256; g.lbl = 256;
    g.K = 256; g.ksplit = 1; g.kchunk = 256; g.bt0 = 0; g.bt1 = 0;
    g.o0 = FB; g.o1 = FB + 4L * 128 * 2304; g.so = 128L * 2304;
    g.p0 = FLO; g.p1 = FLO + 4L * 128 * 2304; g.sp = 128L * 2304;
    g.q0 = FTB; g.q1 = FTB + 4L * 2304 * 256; g.sq = 2304L * 256;
    g.u0 = FTLO; g.u1 = FTLO + 4L * 2304 * 128; g.su = 2304L * 128;
    g.aux0 = BPRE; g.aux1 = BPRE + 256; g.saux = 0;
    mgemm<0, 1, 32><<<dim3(18, 2, 8), 256, 0, stream>>>(g); }

  { GArgs g{};  // e_time (split, BK=32, K-split 36, private partials)
    g.a0 = g.a1 = FB; g.al0 = g.al1 = FLO;
    g.sa = g.sal = 128L * 2304; g.lda = g.lal = 2304;
    g.b0 = g.b1 = FB + 4L * 128 * 2304; g.bl0 = g.bl1 = FLO + 4L * 128 * 2304;
    g.sb = g.sbl = 128L * 2304; g.ldb = g.lbl = 2304;
    g.K = 2304; g.ksplit = 36; g.kchunk = 64; g.bt0 = 0; g.bt1 = 0;
    g.o0 = g.o1 = YTF; g.so = 16384;
    mgemm<1, 1, 32><<<dim3(1, 1, 144), 256, 0, stream>>>(g); }

  ereduce<<<256, 256, 0, stream>>>(YTF, ET);
  et_softmax<<<4, 256, 0, stream>>>(ET, MB);

  { GArgs g{};  // e_space (split, BK=32): PT + CS/RS partials
    g.a0 = g.a1 = FTB + 128; g.al0 = g.al1 = FTLO;
    g.sa = 2304L * 256; g.sal = 2304L * 128; g.lda = 256; g.lal = 128;
    g.b0 = g.b1 = FTB + 4L * 2304 * 256 + 128; g.bl0 = g.bl1 = FTLO + 4L * 2304 * 128;
    g.sb = 2304L * 256; g.sbl = 2304L * 128; g.ldb = 256; g.lbl = 128;
    g.K = 128; g.ksplit = 1; g.kchunk = 128; g.bt0 = 0; g.bt1 = 0;
    g.o0 = g.o1 = PT; g.so = (long)2304 * 2304;
    g.p0 = CSP; g.q0 = RSP;
    mgemm<2, 1, 32><<<dim3(18, 18, 4), 256, 0, stream>>>(g); }

  csrs_reduce<<<72, 256, 0, stream>>>(CSP, RSP, CS, RS);

  { GArgs g{};  // A-gemms
    g.a0 = MB; g.a1 = MB + 4 * 16384; g.sa = 16384; g.lda = 128;
    g.b0 = FTB; g.b1 = FTB + 4L * 2304 * 256; g.sb = 2304L * 256; g.ldb = 256;
    g.K = 128; g.ksplit = 1; g.kchunk = 128; g.bt0 = 0; g.bt1 = 0;
    g.o0 = AB; g.o1 = AB + 4L * 128 * 2304; g.so = 128L * 2304;
    mgemm<3, 0, 64><<<dim3(18, 1, 8), 256, 0, stream>>>(g); }

  { GArgs g{};  // y-gemms split-K 3 private
    g.a0 = AB; g.a1 = AB + 4L * 128 * 2304; g.sa = 128L * 2304; g.lda = 2304;
    g.b0 = g.b1 = PT; g.sb = (long)2304 * 2304; g.ldb = 2304;
    g.K = 2304; g.ksplit = 3; g.kchunk = 768; g.bt0 = 0; g.bt1 = 1;
    g.o0 = g.o1 = YTF; g.so = 2304L * 128;
    mgemm<6, 0, 64><<<dim3(18, 1, 24), 256, 0, stream>>>(g); }

  yreduce<<<1152, 256, 0, stream>>>(YTF, CS, RS, YT);

  { GArgs g{};  // post convs
    g.a0 = WPOSTB; g.a1 = WPOSTB + 32768; g.sa = 0; g.lda = 128;
    g.b0 = YT; g.b1 = YT + 4L * 2304 * 128; g.sb = 2304L * 128; g.ldb = 128;
    g.K = 128; g.ksplit = 1; g.kchunk = 128; g.bt0 = 0; g.bt1 = 0;
    g.o0 = out; g.o1 = out + 4L * 256 * 2304; g.so = 256L * 2304;
    g.aux0 = BPOST; g.aux1 = BPOST + 256; g.saux = 0;
    g.res0 = x1; g.res1 = x2; g.sres = 256L * 2304;
    mgemm<5, 0, 64><<<dim3(18, 2, 8), 256, 0, stream>>>(g); }
}